// Round 4
// baseline (546.790 us; speedup 1.0000x reference)
//
#include <hip/hip_runtime.h>
#include <hip/hip_bf16.h>

// GGNN fused scan v7. B=128, N=128, E=64, T=32, R=32.
// ggnn_pre: unchanged from v4/v6.
// ggnn_main v7: 2 barriers/step, software-pipelined max phase.
//   - H in registers: w0 owns j[0,32), w1 [32,64), w3 [64,128) (2 chunks);
//     w2 owns nothing (it is the gate wave). Lane (p=e&31, half=e>>5) holds
//     e-pair (2p,2p+1) for 16 j per chunk.
//   - The bulk max for step i+1 runs DURING step i's gate phases on idle
//     waves (only col j==i is fresh; it's masked out and patched at the top
//     of step i+1 from updHrow in e-layout -> no bpermute on the patch).
//   - Step: top{pmax combine + scol patch + owner merge} ->
//     G1{w0 r-gate | w1 z-gate | w3 max chunk0} -> C ->
//     G2{w2 t-gate+upd+upd@Win | w0,w1,w3 max partials + pmax write} -> A.
//   - pmax double-buffered by step parity. Raw s_barrier + lgkmcnt only;
//     NT global prefetch stays in flight across barriers.

#define B_ 128
#define N_ 128

typedef unsigned short u16;
typedef unsigned int u32;

__device__ __forceinline__ float b2f(u16 u) {
    union { u32 i; float f; } c; c.i = ((u32)u) << 16; return c.f;
}
__device__ __forceinline__ u16 f2b(float f) {
    union { float f; u32 i; } c; c.f = f;
    u32 u = c.i;
    return (u16)((u + 0x7fffu + ((u >> 16) & 1u)) >> 16);
}
__device__ __forceinline__ float sigmoidf_(float x) { return 1.0f / (1.0f + __expf(-x)); }
__device__ __forceinline__ float tanhf_(float x) { return 1.0f - 2.0f / (__expf(2.0f * x) + 1.0f); }
__device__ __forceinline__ float rlane(float v, int k) {
    return __int_as_float(__builtin_amdgcn_readlane(__float_as_int(v), k));
}
// wave barrier: order LDS only; global loads stay in flight
#define BARRIER() asm volatile("s_waitcnt lgkmcnt(0)\n\ts_barrier" ::: "memory")

// 64-k readlane matvec with per-wave register column
__device__ __forceinline__ float rmv(float v, const float (&wc)[64], float a0i) {
    float a0 = a0i, a1 = 0.f, a2 = 0.f, a3 = 0.f;
    #pragma unroll
    for (int k = 0; k < 64; k += 4) {
        a0 += rlane(v, k)     * wc[k];
        a1 += rlane(v, k + 1) * wc[k + 1];
        a2 += rlane(v, k + 2) * wc[k + 2];
        a3 += rlane(v, k + 3) * wc[k + 3];
    }
    return (a0 + a1) + (a2 + a3);
}

// partial max over one 16-j chunk (pair layout). Col S masked (-1 = none).
__device__ __forceinline__ void chunk_max(
    const unsigned char* __restrict__ relLrow, const u32* __restrict__ relW32p,
    const float* __restrict__ discp, int S, int jb, int p,
    const float (&hAq)[16], const float (&hBq)[16], float& mA, float& mB)
{
    uint4 rv = *(const uint4*)(relLrow + jb);
    u32 rvw[4] = {rv.x, rv.y, rv.z, rv.w};
    const int Sw = S >> 2;
    const u32 km = ~(0xFFu << ((S & 3) * 8));
    #pragma unroll
    for (int g = 0; g < 4; ++g) {
        u32 d = rvw[g];
        d = ((jb >> 2) + g == Sw) ? (d & km) : d;
        #pragma unroll
        for (int bb = 0; bb < 4; ++bb) {
            const int jj = 4 * g + bb;
            u32 rr = (d >> (bb * 8)) & 255u;
            u32 pr = relW32p[(rr << 5) + p];
            float rwbA = __uint_as_float(pr << 16);
            float rwbB = __uint_as_float(pr & 0xffff0000u);
            float dd = discp[jb + jj];
            float sA = fmaxf(hAq[jj] + rwbA, 0.f) * dd;
            float sB = fmaxf(hBq[jj] + rwbB, 0.f) * dd;
            mA = rr ? fmaxf(mA, sA) : mA;
            mB = rr ? fmaxf(mB, sB) : mB;
        }
    }
}

// pair-layout partial -> lane-e max, written to pmax slot
__device__ __forceinline__ void combine_write(float mA, float mB, int e,
                                              float* __restrict__ slotbase)
{
    int s0 = (e >> 1) << 2, s1 = ((e >> 1) + 32) << 2;
    float v0a = __int_as_float(__builtin_amdgcn_ds_bpermute(s0, __float_as_int(mA)));
    float v0b = __int_as_float(__builtin_amdgcn_ds_bpermute(s0, __float_as_int(mB)));
    float v1a = __int_as_float(__builtin_amdgcn_ds_bpermute(s1, __float_as_int(mA)));
    float v1b = __int_as_float(__builtin_amdgcn_ds_bpermute(s1, __float_as_int(mB)));
    float c0 = (e & 1) ? v0b : v0a;
    float c1 = (e & 1) ? v1b : v1a;
    slotbase[e] = fmaxf(c0, c1);
}

// ---------------- precompute kernel (unchanged) ----------------
__global__ __launch_bounds__(256, 2) void ggnn_pre(
    const int* __restrict__ node_slice, const int* __restrict__ type_slice,
    const float* __restrict__ emb_table, const float* __restrict__ type_table,
    const float* __restrict__ W_in,
    const float* __restrict__ Wr, const float* __restrict__ br,
    const float* __restrict__ Wz, const float* __restrict__ bz,
    const float* __restrict__ Wt, const float* __restrict__ bt,
    u16* __restrict__ NTbf, float* __restrict__ Hws)
{
    const int b  = blockIdx.x >> 3;
    const int i0 = (blockIdx.x & 7) * 16;
    const int t = threadIdx.x;
    const int w = t >> 6;
    const int e = t & 63;

    float wc[96];
    float bias = 0.f;
    if (w < 3) {
        const float* W  = (w == 0) ? Wr : (w == 1) ? Wz : Wt;
        const float* bb = (w == 0) ? br : (w == 1) ? bz : bt;
        bias = bb[e];
        #pragma unroll
        for (int k = 0; k < 96; ++k) wc[k] = W[k * 64 + e];
    } else {
        #pragma unroll
        for (int k = 0; k < 64; ++k) wc[k] = W_in[k * 64 + e];
        #pragma unroll
        for (int k = 64; k < 96; ++k) wc[k] = 0.f;
    }

    for (int rr = 0; rr < 16; ++rr) {
        const int row = i0 + rr;
        const int node = node_slice[b * N_ + row];
        const float* ep = emb_table + node * 64;
        if (w < 3) {
            const int typ = type_slice[b * N_ + row];
            const float* tp = type_table + typ * 32;
            float a0 = bias, a1 = 0.f, a2 = 0.f, a3 = 0.f;
            #pragma unroll
            for (int k = 0; k < 32; k += 4) {
                a0 += tp[k]   * wc[k];
                a1 += tp[k+1] * wc[k+1];
                a2 += tp[k+2] * wc[k+2];
                a3 += tp[k+3] * wc[k+3];
            }
            #pragma unroll
            for (int k = 0; k < 64; k += 4) {
                a0 += ep[k]   * wc[32+k];
                a1 += ep[k+1] * wc[32+k+1];
                a2 += ep[k+2] * wc[32+k+2];
                a3 += ep[k+3] * wc[32+k+3];
            }
            NTbf[(b * N_ + row) * 192 + w * 64 + e] = f2b((a0 + a1) + (a2 + a3));
        } else {
            float a0 = 0.f, a1 = 0.f, a2 = 0.f, a3 = 0.f;
            #pragma unroll
            for (int k = 0; k < 64; k += 4) {
                a0 += ep[k]   * wc[k];
                a1 += ep[k+1] * wc[k+1];
                a2 += ep[k+2] * wc[k+2];
                a3 += ep[k+3] * wc[k+3];
            }
            Hws[(b * N_ + row) * 64 + e] = (a0 + a1) + (a2 + a3);
        }
    }
}

// ---------------- main scan kernel ----------------
__global__ __launch_bounds__(256, 1) void ggnn_main(
    const int* __restrict__ rel_matrix,
    const int* __restrict__ input_length, const float* __restrict__ distance,
    const float* __restrict__ rel_table,
    const float* __restrict__ W_in, const float* __restrict__ b_in,
    const float* __restrict__ Wr, const float* __restrict__ Wz, const float* __restrict__ Wt,
    const float* __restrict__ W_co, const float* __restrict__ b_co,
    const float* __restrict__ W1, const float* __restrict__ b1,
    const float* __restrict__ W2, const float* __restrict__ b2,
    const float* __restrict__ W3, const float* __restrict__ b3,
    const float* __restrict__ W4, const float* __restrict__ b4,
    const u16* __restrict__ NTbf, const float* __restrict__ Hws,
    float* __restrict__ out)
{
    __shared__ __align__(16) u32   relW32[51 * 32];       // 6.4 KB pair bf16
    __shared__ __align__(16) float relWbF[51 * 64];       // 13 KB e-layout f32
    __shared__ __align__(16) unsigned char relL[128 * 128]; // 16 KB len-masked
    __shared__ __align__(16) float disc[N_];
    __shared__ __align__(16) float pmaxL[2][192];         // dbl-buffered, 3 slots
    __shared__ __align__(16) float r_row[64], z_row[64], updHrow[64];
    __shared__ __align__(16) float userrow[64], itemrow[64], submrow[64];
    __shared__ __align__(16) float temp[192];
    __shared__ float h1[128];
    __shared__ float h2v[64];
    __shared__ float h3v[32];

    const int b = blockIdx.x;
    const int t = threadIdx.x;
    const int w = t >> 6;
    const int e = t & 63;
    const int p = e & 31;
    const int half = e >> 5;
    const int len = input_length[b];
    const float NEGINF = -__builtin_inff();

    // j-chunk bases: w0 [0,32), w1 [32,64), w3 [64,128) (chunks 0,1); w2 none
    const int jb0 = (w == 3) ? (64 + 16 * half) : (32 * w + 16 * half);
    const int jb1 = 96 + 16 * half;

    // ---- staging (stage 1: disc, relL, relWbF) ----
    if (t < N_) disc[t] = -0.1f * distance[b * N_ + t];

    {   // rel_matrix -> u8, len-masked
        const int4* src = (const int4*)(rel_matrix + b * N_ * N_);
        u32* dst = (u32*)relL;
        for (int c = t; c < 4096; c += 256) {
            int4 v = src[c];
            int j = (c * 4) & 127;
            u32 pk = (u32)((j + 0 < len && v.x) ? v.x : 0)
                   | ((u32)((j + 1 < len && v.y) ? v.y : 0) << 8)
                   | ((u32)((j + 2 < len && v.z) ? v.z : 0) << 16)
                   | ((u32)((j + 3 < len && v.w) ? v.w : 0) << 24);
            dst[c] = pk;
        }
    }
    for (int idx = t; idx < 51 * 64; idx += 256) {        // relWbF (bf16-rounded)
        int r = idx >> 6, ee = idx & 63;
        float acc = b_in[ee];
        #pragma unroll
        for (int k = 0; k < 32; ++k)
            acc += rel_table[r * 32 + k] * W_in[(64 + k) * 64 + ee];
        relWbF[idx] = b2f(f2b(acc));
    }

    // per-wave weight columns (global, no LDS dep)
    float wcolA[64], wcolB[64];
    {
        const float* wsA = (w == 0) ? (Wr + 96 * 64) : (w == 1) ? (Wz + 96 * 64)
                                                     : (Wt + 96 * 64);
        #pragma unroll
        for (int k = 0; k < 64; ++k) wcolA[k] = wsA[k * 64 + e];
        #pragma unroll
        for (int k = 0; k < 64; ++k) wcolB[k] = W_in[k * 64 + e];
    }

    // H registers (global, no LDS dep)
    float hA0[16], hB0[16], hA1[16], hB1[16];
    {
        const float2* H2 = (const float2*)(Hws + (size_t)b * N_ * 64);
        if (w != 2) {
            #pragma unroll
            for (int jj = 0; jj < 16; ++jj) {
                float2 v = H2[(jb0 + jj) * 32 + p];
                hA0[jj] = v.x; hB0[jj] = v.y;
            }
        }
        if (w == 3) {
            #pragma unroll
            for (int jj = 0; jj < 16; ++jj) {
                float2 v = H2[(jb1 + jj) * 32 + p];
                hA1[jj] = v.x; hB1[jj] = v.y;
            }
        }
    }

    // NT prefetch (step 0)
    const u16* NTb = NTbf + (size_t)b * N_ * 192;
    u16 ntc = 0;
    if (w < 3) ntc = NTb[w * 64 + e];
    float user_r = 0.f, item_r = 0.f, subm_r = NEGINF;

    __syncthreads();                                      // stage1 done

    // stage 2: pack pair-bf16 relW32 from relWbF
    for (int idx = t; idx < 51 * 32; idx += 256) {
        int r = idx >> 5, pp = idx & 31;
        u16 lo = f2b(relWbF[(r << 6) + 2 * pp]);
        u16 hi = f2b(relWbF[(r << 6) + 2 * pp + 1]);
        relW32[idx] = (u32)lo | ((u32)hi << 16);
    }
    __syncthreads();                                      // stage2 done

    // initial full partial max for step 0 (no masked col)
    {
        float mA = NEGINF, mB = NEGINF;
        if (w != 2) {
            chunk_max(relL, relW32, disc, -1, jb0, p, hA0, hB0, mA, mB);
            if (w == 3)
                chunk_max(relL, relW32, disc, -1, jb1, p, hA1, hB1, mA, mB);
            combine_write(mA, mB, e, pmaxL[0] + ((w == 3) ? 128 : (w << 6)));
        }
    }
    __syncthreads();                                      // pmax[0] ready

    // ---- scan ----
    for (int i = 0; i < len; ++i) {
        const int par = i & 1;

        // NT prefetch for step i+1 (stays in flight across raw barriers)
        u16 ntp = 0;
        if (w < 3) ntp = NTb[((i + 1) & 127) * 192 + w * 64 + e];

        // top: dis0 = combine(pmax) + fresh-col patch; owner merges row i-1
        float mm = fmaxf(fmaxf(pmaxL[par][e], pmaxL[par][64 + e]),
                         pmaxL[par][128 + e]);
        if (i > 0) {
            const int prev = i - 1;
            const int rb = relL[i * N_ + prev];            // uniform broadcast
            if (rb) {
                float sc = fmaxf(updHrow[e] + relWbF[(rb << 6) + e], 0.f)
                           * disc[prev];
                mm = fmaxf(mm, sc);
            }
            const int ow = (prev < 32) ? 0 : (prev < 64) ? 1 : 3;
            if (w == ow) {                                 // uniform branch
                float2 u = ((const float2*)updHrow)[p];
                const int off = prev - ((ow == 3) ? 64 : 32 * ow);
                const int hs = (off >> 4) & 1;
                const int oj = off & 15;
                const bool hm = (half == hs);
                if ((off >> 5) == 0) {
                    #pragma unroll
                    for (int jj = 0; jj < 16; ++jj) if (jj == oj) {
                        hA0[jj] = hm ? u.x : hA0[jj];
                        hB0[jj] = hm ? u.y : hB0[jj];
                    }
                } else {
                    #pragma unroll
                    for (int jj = 0; jj < 16; ++jj) if (jj == oj) {
                        hA1[jj] = hm ? u.x : hA1[jj];
                        hB1[jj] = hm ? u.y : hB1[jj];
                    }
                }
            }
        }
        const float dis0 = (mm == NEGINF) ? 0.f : mm;

        float mA = NEGINF, mB = NEGINF;
        const bool doPart = (i + 1 < len);                 // uniform
        const unsigned char* rl1 = relL + (i + 1) * N_;

        // G1: gates r,z | w3 max chunk0 for i+1
        if (w == 0) {
            r_row[e] = sigmoidf_(rmv(dis0, wcolA, b2f(ntc)));
        } else if (w == 1) {
            z_row[e] = sigmoidf_(rmv(dis0, wcolA, b2f(ntc)));
        } else if (w == 3 && doPart) {
            chunk_max(rl1, relW32, disc, i, jb0, p, hA0, hB0, mA, mB);
        }
        BARRIER();                                        // C

        // G2: w2 t-gate + upd + upd@Win | w0,w1,w3 max partials for i+1
        if (w == 2) {
            float rdp = r_row[e] * dis0;
            float hh = tanhf_(rmv(rdp, wcolA, b2f(ntc)));
            float z = z_row[e];
            float upd = (1.f - z) * dis0 + z * hh;
            updHrow[e] = rmv(upd, wcolB, 0.f);
            if (i == 0) user_r = upd;
            subm_r = fmaxf(subm_r, upd);
            item_r = upd;
        } else if (doPart) {
            if (w == 3) chunk_max(rl1, relW32, disc, i, jb1, p, hA1, hB1, mA, mB);
            else        chunk_max(rl1, relW32, disc, i, jb0, p, hA0, hB0, mA, mB);
            combine_write(mA, mB, e, pmaxL[par ^ 1] + ((w == 3) ? 128 : (w << 6)));
        }
        ntc = ntp;
        BARRIER();                                        // A (loop top)
    }

    if (w == 2) { userrow[e] = user_r; itemrow[e] = item_r; submrow[e] = subm_r; }
    __syncthreads();

    // ---- epilogue ----
    if (t < 128) {
        const int half2 = t >> 6;               // 0: ua*user, 1: ia*item
        const float* row = (half2 == 0) ? userrow : itemrow;
        float acc = b_co[e];
        #pragma unroll
        for (int k = 0; k < 64; ++k) acc += row[k] * W_co[k * 64 + e];
        #pragma unroll
        for (int k = 0; k < 64; ++k) acc += submrow[k] * W_co[(64 + k) * 64 + e];
        float act = fmaxf(acc, 0.f);
        temp[half2 * 128 + e] = act * row[e];
    } else if (t < 192) {
        temp[64 + (t - 128)] = submrow[t - 128];
    }
    __syncthreads();

    if (t < 128) {
        float acc = b1[t];
        for (int k = 0; k < 192; ++k) acc += temp[k] * W1[k * 128 + t];
        h1[t] = fmaxf(acc, 0.f);
    }
    __syncthreads();
    if (t < 64) {
        float acc = b2[t];
        for (int k = 0; k < 128; ++k) acc += h1[k] * W2[k * 64 + t];
        h2v[t] = fmaxf(acc, 0.f);
    }
    __syncthreads();
    if (t < 32) {
        float acc = b3[t];
        for (int k = 0; k < 64; ++k) acc += h2v[k] * W3[k * 32 + t];
        h3v[t] = fmaxf(acc, 0.f);
    }
    __syncthreads();
    if (t == 0) {
        float acc = b4[0];
        for (int k = 0; k < 32; ++k) acc += h3v[k] * W4[k];
        out[b] = sigmoidf_(acc);
    }
}

extern "C" void kernel_launch(void* const* d_in, const int* in_sizes, int n_in,
                              void* d_out, int out_size, void* d_ws, size_t ws_size,
                              hipStream_t stream)
{
    const int*   node_slice = (const int*)d_in[0];
    const int*   type_slice = (const int*)d_in[1];
    const float* distance   = (const float*)d_in[2];
    const int*   rel_matrix = (const int*)d_in[3];
    const int*   input_len  = (const int*)d_in[4];
    // d_in[5] = isBatch (ignored)
    const float* emb_table  = (const float*)d_in[6];
    const float* type_table = (const float*)d_in[7];
    const float* rel_table  = (const float*)d_in[8];
    const float* W_in = (const float*)d_in[9];  const float* b_in = (const float*)d_in[10];
    const float* Wr   = (const float*)d_in[11]; const float* br   = (const float*)d_in[12];
    const float* Wz   = (const float*)d_in[13]; const float* bz   = (const float*)d_in[14];
    const float* Wt   = (const float*)d_in[15]; const float* bt   = (const float*)d_in[16];
    const float* W_co = (const float*)d_in[17]; const float* b_co = (const float*)d_in[18];
    const float* W1   = (const float*)d_in[19]; const float* b1   = (const float*)d_in[20];
    const float* W2   = (const float*)d_in[21]; const float* b2   = (const float*)d_in[22];
    const float* W3   = (const float*)d_in[23]; const float* b3   = (const float*)d_in[24];
    const float* W4   = (const float*)d_in[25]; const float* b4   = (const float*)d_in[26];

    u16*   NTbf = (u16*)d_ws;                            // 128*128*192 bf16 = 6.29 MB
    float* Hws  = (float*)((char*)d_ws + (size_t)B_ * N_ * 192 * 2); // 4.19 MB

    ggnn_pre<<<dim3(1024), dim3(256), 0, stream>>>(
        node_slice, type_slice, emb_table, type_table,
        W_in, Wr, br, Wz, bz, Wt, bt, NTbf, Hws);

    ggnn_main<<<dim3(B_), dim3(256), 0, stream>>>(
        rel_matrix, input_len, distance, rel_table,
        W_in, b_in, Wr, Wz, Wt, W_co, b_co,
        W1, b1, W2, b2, W3, b3, W4, b4,
        NTbf, Hws, (float*)d_out);
}

// Round 5
// 460.296 us; speedup vs baseline: 1.1879x; 1.1879x over previous
//
#include <hip/hip_runtime.h>
#include <hip/hip_bf16.h>

// GGNN fused scan v8. B=128, N=128, E=64, T=32, R=32.
// ggnn_main: exact revert to v6 (best measured: 262.7us, 0 bank conflicts).
// ggnn_pre v2: throughput rewrite. 2048 blocks x 8 rows (was 1024 x 16).
//   Per row, the 96 inputs [type(32)|emb(64)] are fetched with PER-LANE
//   vector loads (xa: lanes 0-31 tp, lanes 32-63 ep[0:32); xb: ep[32:64)),
//   all 16 loads issued up-front per wave -> deep vmcnt pipelining, no
//   dependence on compiler scalar-path uniformity analysis. Compute is a
//   readlane matvec with accumulation order IDENTICAL to v4-v7 pre.

#define B_ 128
#define N_ 128

typedef unsigned short u16;
typedef unsigned int u32;

__device__ __forceinline__ float b2f(u16 u) {
    union { u32 i; float f; } c; c.i = ((u32)u) << 16; return c.f;
}
__device__ __forceinline__ u16 f2b(float f) {
    union { float f; u32 i; } c; c.f = f;
    u32 u = c.i;
    return (u16)((u + 0x7fffu + ((u >> 16) & 1u)) >> 16);
}
__device__ __forceinline__ float sigmoidf_(float x) { return 1.0f / (1.0f + __expf(-x)); }
__device__ __forceinline__ float tanhf_(float x) { return 1.0f - 2.0f / (__expf(2.0f * x) + 1.0f); }
__device__ __forceinline__ float rlane(float v, int k) {
    return __int_as_float(__builtin_amdgcn_readlane(__float_as_int(v), k));
}
// wave-local barrier: LDS ordering only, vmem loads stay in flight
#define BARRIER() asm volatile("s_waitcnt lgkmcnt(0)\n\ts_barrier" ::: "memory")

// 64-k readlane matvec with per-wave register column
__device__ __forceinline__ float rmv(float v, const float (&wc)[64], float a0i) {
    float a0 = a0i, a1 = 0.f, a2 = 0.f, a3 = 0.f;
    #pragma unroll
    for (int k = 0; k < 64; k += 4) {
        a0 += rlane(v, k)     * wc[k];
        a1 += rlane(v, k + 1) * wc[k + 1];
        a2 += rlane(v, k + 2) * wc[k + 2];
        a3 += rlane(v, k + 3) * wc[k + 3];
    }
    return (a0 + a1) + (a2 + a3);
}

// ---------------- precompute kernel v2 ----------------
__global__ __launch_bounds__(256, 2) void ggnn_pre(
    const int* __restrict__ node_slice, const int* __restrict__ type_slice,
    const float* __restrict__ emb_table, const float* __restrict__ type_table,
    const float* __restrict__ W_in,
    const float* __restrict__ Wr, const float* __restrict__ br,
    const float* __restrict__ Wz, const float* __restrict__ bz,
    const float* __restrict__ Wt, const float* __restrict__ bt,
    u16* __restrict__ NTbf, float* __restrict__ Hws)
{
    const int b  = blockIdx.x >> 4;         // 16 blocks per batch
    const int i0 = (blockIdx.x & 15) * 8;   // 8 rows per block
    const int t = threadIdx.x;
    const int w = t >> 6;
    const int e = t & 63;

    // per-wave weight column (registers), as in v4-v7
    float wc[96];
    float bias = 0.f;
    if (w < 3) {
        const float* W  = (w == 0) ? Wr : (w == 1) ? Wz : Wt;
        const float* bb = (w == 0) ? br : (w == 1) ? bz : bt;
        bias = bb[e];
        #pragma unroll
        for (int k = 0; k < 96; ++k) wc[k] = W[k * 64 + e];
    } else {
        #pragma unroll
        for (int k = 0; k < 64; ++k) wc[k] = W_in[k * 64 + e];
        #pragma unroll
        for (int k = 64; k < 96; ++k) wc[k] = 0.f;
    }

    // row indices (independent small loads)
    int nodes[8], typs[8];
    #pragma unroll
    for (int r = 0; r < 8; ++r) {
        nodes[r] = node_slice[b * N_ + i0 + r];
        typs[r]  = type_slice[b * N_ + i0 + r];
    }

    // gather: per-lane vector loads, all 16 issued up-front
    // xa[r]: lanes 0-31 = tp[0..32), lanes 32-63 = ep[0..32)
    // xb[r]: lanes 0-31 = ep[32..64) (lanes 32-63 duplicate, unused)
    float xa[8], xb[8];
    #pragma unroll
    for (int r = 0; r < 8; ++r) {
        const float* pa = (e < 32)
            ? (type_table + (size_t)typs[r] * 32 + e)
            : (emb_table + (size_t)nodes[r] * 64 + (e - 32));
        xa[r] = *pa;
        xb[r] = emb_table[(size_t)nodes[r] * 64 + 32 + (e & 31)];
    }

    #pragma unroll
    for (int r = 0; r < 8; ++r) {
        if (w < 3) {
            float a0 = bias, a1 = 0.f, a2 = 0.f, a3 = 0.f;
            #pragma unroll
            for (int k = 0; k < 32; k += 4) {          // tp part
                a0 += rlane(xa[r], k)     * wc[k];
                a1 += rlane(xa[r], k + 1) * wc[k + 1];
                a2 += rlane(xa[r], k + 2) * wc[k + 2];
                a3 += rlane(xa[r], k + 3) * wc[k + 3];
            }
            #pragma unroll
            for (int k = 0; k < 32; k += 4) {          // ep[0..32)
                a0 += rlane(xa[r], 32 + k)     * wc[32 + k];
                a1 += rlane(xa[r], 32 + k + 1) * wc[32 + k + 1];
                a2 += rlane(xa[r], 32 + k + 2) * wc[32 + k + 2];
                a3 += rlane(xa[r], 32 + k + 3) * wc[32 + k + 3];
            }
            #pragma unroll
            for (int k = 32; k < 64; k += 4) {         // ep[32..64)
                a0 += rlane(xb[r], k - 32) * wc[32 + k];
                a1 += rlane(xb[r], k - 31) * wc[32 + k + 1];
                a2 += rlane(xb[r], k - 30) * wc[32 + k + 2];
                a3 += rlane(xb[r], k - 29) * wc[32 + k + 3];
            }
            NTbf[(size_t)(b * N_ + i0 + r) * 192 + w * 64 + e] =
                f2b((a0 + a1) + (a2 + a3));
        } else {
            float a0 = 0.f, a1 = 0.f, a2 = 0.f, a3 = 0.f;
            #pragma unroll
            for (int k = 0; k < 32; k += 4) {          // ep[0..32)
                a0 += rlane(xa[r], 32 + k)     * wc[k];
                a1 += rlane(xa[r], 32 + k + 1) * wc[k + 1];
                a2 += rlane(xa[r], 32 + k + 2) * wc[k + 2];
                a3 += rlane(xa[r], 32 + k + 3) * wc[k + 3];
            }
            #pragma unroll
            for (int k = 32; k < 64; k += 4) {         // ep[32..64)
                a0 += rlane(xb[r], k - 32) * wc[k];
                a1 += rlane(xb[r], k - 31) * wc[k + 1];
                a2 += rlane(xb[r], k - 30) * wc[k + 2];
                a3 += rlane(xb[r], k - 29) * wc[k + 3];
            }
            Hws[(size_t)(b * N_ + i0 + r) * 64 + e] = (a0 + a1) + (a2 + a3);
        }
    }
}

// ---------------- main scan kernel (exact v6) ----------------
__global__ __launch_bounds__(256, 1) void ggnn_main(
    const int* __restrict__ rel_matrix,
    const int* __restrict__ input_length, const float* __restrict__ distance,
    const float* __restrict__ rel_table,
    const float* __restrict__ W_in, const float* __restrict__ b_in,
    const float* __restrict__ Wr, const float* __restrict__ Wz, const float* __restrict__ Wt,
    const float* __restrict__ W_co, const float* __restrict__ b_co,
    const float* __restrict__ W1, const float* __restrict__ b1,
    const float* __restrict__ W2, const float* __restrict__ b2,
    const float* __restrict__ W3, const float* __restrict__ b3,
    const float* __restrict__ W4, const float* __restrict__ b4,
    const u16* __restrict__ NTbf, const float* __restrict__ Hws,
    float* __restrict__ out)
{
    __shared__ __align__(16) u32   relW32[51 * 32];       // 6.4 KB, [r][e-pair]
    __shared__ __align__(16) unsigned char relL[128 * 128]; // 16 KB, len-masked
    __shared__ __align__(16) float disc[N_];
    __shared__ __align__(16) float pmax[256];
    __shared__ __align__(16) float r_row[64], z_row[64], v2row[64];
    __shared__ __align__(16) float updH1[64], updH2[64];
    __shared__ __align__(16) float userrow[64], itemrow[64], submrow[64];
    __shared__ __align__(16) float temp[192];
    __shared__ float h1[128];
    __shared__ float h2v[64];
    __shared__ float h3v[32];

    const int b = blockIdx.x;
    const int t = threadIdx.x;
    const int w = t >> 6;
    const int e = t & 63;
    const int len = input_length[b];
    const float NEGINF = -__builtin_inff();

    // ---- staging ----
    if (t < N_) disc[t] = -0.1f * distance[b * N_ + t];

    {   // rel_matrix -> u8, len-masked
        const int4* src = (const int4*)(rel_matrix + b * N_ * N_);
        u32* dst = (u32*)relL;
        for (int c = t; c < 4096; c += 256) {
            int4 v = src[c];
            int j = (c * 4) & 127;
            u32 pk = (u32)((j + 0 < len && v.x) ? v.x : 0)
                   | ((u32)((j + 1 < len && v.y) ? v.y : 0) << 8)
                   | ((u32)((j + 2 < len && v.z) ? v.z : 0) << 16)
                   | ((u32)((j + 3 < len && v.w) ? v.w : 0) << 24);
            dst[c] = pk;
        }
    }
    for (int idx = t; idx < 51 * 32; idx += 256) {        // relW32 = b_in + rel@W_in_bot
        int r = idx >> 5, pp = idx & 31;
        float aA = b_in[2 * pp], aB = b_in[2 * pp + 1];
        #pragma unroll
        for (int k = 0; k < 32; ++k) {
            float rt = rel_table[r * 32 + k];
            aA += rt * W_in[(64 + k) * 64 + 2 * pp];
            aB += rt * W_in[(64 + k) * 64 + 2 * pp + 1];
        }
        relW32[idx] = (u32)f2b(aA) | ((u32)f2b(aB) << 16);
    }

    // per-wave weight column: w0=Wr_bot, w1=Wz_bot, w2=Wt_bot, w3=W_in_top
    float wcol[64];
    {
        const float* wsrc = (w == 0) ? (Wr + 96 * 64) : (w == 1) ? (Wz + 96 * 64)
                          : (w == 2) ? (Wt + 96 * 64) : W_in;
        #pragma unroll
        for (int k = 0; k < 64; ++k) wcol[k] = wsrc[k * 64 + e];
    }

    // H in registers: lane (p,half) of wave w holds e-pair (2p,2p+1) for
    // j = jbase..jbase+15, jbase = 32w + 16*half.
    const int p = e & 31;
    const int half = e >> 5;
    const int jbase = w * 32 + half * 16;
    float hA[16], hB[16];
    {
        const float2* H2 = (const float2*)(Hws + (size_t)b * N_ * 64);
        #pragma unroll
        for (int jj = 0; jj < 16; ++jj) {
            float2 v = H2[(jbase + jj) * 32 + p];
            hA[jj] = v.x; hB[jj] = v.y;
        }
    }

    // NT prefetch (step 0)
    const u16* NTb = NTbf + (size_t)b * N_ * 192;
    u16 ntc = 0;
    if (w < 3) ntc = NTb[w * 64 + e];
    float user_r = 0.f, item_r = 0.f, subm_r = NEGINF;
    __syncthreads();                                      // A0 (full drain)

    float dregp[16];
    #pragma unroll
    for (int jj = 0; jj < 16; ++jj) dregp[jj] = disc[jbase + jj];

    // ---- scan ----
    for (int i = 0; i < len; ++i) {
        // NT prefetch for step i+1 (raw barriers keep it in flight)
        u16 ntp = 0;
        if (w < 3) ntp = NTb[((i + 1) & 127) * 192 + w * 64 + e];

        // rel row for this wave's 32 j (one b128, uniform-per-half addr)
        uint4 rvv = *(const uint4*)(relL + i * N_ + jbase);
        const u32 rvw[4] = {rvv.x, rvv.y, rvv.z, rvv.w};

        // owner wave merges H row i-1 (computed last step as part1+part2)
        if (i > 0) {
            const int prev = i - 1;
            if (w == (prev >> 5)) {
                float2 u1 = ((const float2*)updH1)[p];
                float2 u2 = ((const float2*)updH2)[p];
                float nhA = u1.x + u2.x, nhB = u1.y + u2.y;
                bool hm = (half == ((prev >> 4) & 1));
                const int oj = prev & 15;
                #pragma unroll
                for (int jj = 0; jj < 16; ++jj) {
                    if (jj == oj) {
                        hA[jj] = hm ? nhA : hA[jj];
                        hB[jj] = hm ? nhB : hB[jj];
                    }
                }
            }
        }

        // max phase over this lane's 16 j x 2 e
        float mA = NEGINF, mB = NEGINF;
        #pragma unroll
        for (int jj = 0; jj < 16; ++jj) {
            u32 rr = (rvw[jj >> 2] >> ((jj & 3) * 8)) & 255u;
            u32 pr = relW32[(rr << 5) + p];
            float rwbA = __uint_as_float(pr << 16);
            float rwbB = __uint_as_float(pr & 0xffff0000u);
            float dd = dregp[jj];
            float sA = fmaxf(hA[jj] + rwbA, 0.f) * dd;
            float sB = fmaxf(hB[jj] + rwbB, 0.f) * dd;
            mA = rr ? fmaxf(mA, sA) : mA;
            mB = rr ? fmaxf(mB, sB) : mB;
        }
        // pair-layout -> lane-e: lane e pulls component (e&1) of pair lane
        // (e>>1) from both halves, then maxes.
        {
            int s0 = (e >> 1) << 2, s1 = ((e >> 1) + 32) << 2;
            float v0a = __int_as_float(__builtin_amdgcn_ds_bpermute(s0, __float_as_int(mA)));
            float v0b = __int_as_float(__builtin_amdgcn_ds_bpermute(s0, __float_as_int(mB)));
            float v1a = __int_as_float(__builtin_amdgcn_ds_bpermute(s1, __float_as_int(mA)));
            float v1b = __int_as_float(__builtin_amdgcn_ds_bpermute(s1, __float_as_int(mB)));
            float c0 = (e & 1) ? v0b : v0a;
            float c1 = (e & 1) ? v1b : v1a;
            pmax[(w << 6) + e] = fmaxf(c0, c1);
        }
        BARRIER();                                        // B

        float mm = fmaxf(fmaxf(pmax[e], pmax[64 + e]),
                         fmaxf(pmax[128 + e], pmax[192 + e]));
        float dis0 = (mm == NEGINF) ? 0.f : mm;

        if (w == 0) {                                     // r-gate
            r_row[e] = sigmoidf_(rmv(dis0, wcol, b2f(ntc)));
        } else if (w == 1) {                              // z-gate
            z_row[e] = sigmoidf_(rmv(dis0, wcol, b2f(ntc)));
        }
        BARRIER();                                        // C

        if (w == 2) {                                     // t-gate + update
            float rdp = r_row[e] * dis0;
            float hh = tanhf_(rmv(rdp, wcol, b2f(ntc)));
            float z = z_row[e];
            float zh = z * hh;
            float upd = (1.f - z) * dis0 + zh;
            v2row[e] = zh;
            if (i == 0) user_r = upd;
            subm_r = fmaxf(subm_r, upd);
            item_r = upd;
        } else if (w == 3) {                              // part1 = (1-z)dis0 @ Win
            float v1 = (1.f - z_row[e]) * dis0;
            updH1[e] = rmv(v1, wcol, 0.f);
        }
        BARRIER();                                        // D

        if (w == 3) {                                     // part2 = (z*hh) @ Win
            updH2[e] = rmv(v2row[e], wcol, 0.f);
        }
        ntc = ntp;
        BARRIER();                                        // A (loop top)
    }

    if (w == 2) { userrow[e] = user_r; itemrow[e] = item_r; submrow[e] = subm_r; }
    __syncthreads();

    // ---- epilogue ----
    if (t < 128) {
        const int half2 = t >> 6;               // 0: ua*user, 1: ia*item
        const float* row = (half2 == 0) ? userrow : itemrow;
        float acc = b_co[e];
        #pragma unroll
        for (int k = 0; k < 64; ++k) acc += row[k] * W_co[k * 64 + e];
        #pragma unroll
        for (int k = 0; k < 64; ++k) acc += submrow[k] * W_co[(64 + k) * 64 + e];
        float act = fmaxf(acc, 0.f);
        temp[half2 * 128 + e] = act * row[e];
    } else if (t < 192) {
        temp[64 + (t - 128)] = submrow[t - 128];
    }
    __syncthreads();

    if (t < 128) {
        float acc = b1[t];
        for (int k = 0; k < 192; ++k) acc += temp[k] * W1[k * 128 + t];
        h1[t] = fmaxf(acc, 0.f);
    }
    __syncthreads();
    if (t < 64) {
        float acc = b2[t];
        for (int k = 0; k < 128; ++k) acc += h1[k] * W2[k * 64 + t];
        h2v[t] = fmaxf(acc, 0.f);
    }
    __syncthreads();
    if (t < 32) {
        float acc = b3[t];
        for (int k = 0; k < 64; ++k) acc += h2v[k] * W3[k * 32 + t];
        h3v[t] = fmaxf(acc, 0.f);
    }
    __syncthreads();
    if (t == 0) {
        float acc = b4[0];
        for (int k = 0; k < 32; ++k) acc += h3v[k] * W4[k];
        out[b] = sigmoidf_(acc);
    }
}

extern "C" void kernel_launch(void* const* d_in, const int* in_sizes, int n_in,
                              void* d_out, int out_size, void* d_ws, size_t ws_size,
                              hipStream_t stream)
{
    const int*   node_slice = (const int*)d_in[0];
    const int*   type_slice = (const int*)d_in[1];
    const float* distance   = (const float*)d_in[2];
    const int*   rel_matrix = (const int*)d_in[3];
    const int*   input_len  = (const int*)d_in[4];
    // d_in[5] = isBatch (ignored)
    const float* emb_table  = (const float*)d_in[6];
    const float* type_table = (const float*)d_in[7];
    const float* rel_table  = (const float*)d_in[8];
    const float* W_in = (const float*)d_in[9];  const float* b_in = (const float*)d_in[10];
    const float* Wr   = (const float*)d_in[11]; const float* br   = (const float*)d_in[12];
    const float* Wz   = (const float*)d_in[13]; const float* bz   = (const float*)d_in[14];
    const float* Wt   = (const float*)d_in[15]; const float* bt   = (const float*)d_in[16];
    const float* W_co = (const float*)d_in[17]; const float* b_co = (const float*)d_in[18];
    const float* W1   = (const float*)d_in[19]; const float* b1   = (const float*)d_in[20];
    const float* W2   = (const float*)d_in[21]; const float* b2   = (const float*)d_in[22];
    const float* W3   = (const float*)d_in[23]; const float* b3   = (const float*)d_in[24];
    const float* W4   = (const float*)d_in[25]; const float* b4   = (const float*)d_in[26];

    u16*   NTbf = (u16*)d_ws;                            // 128*128*192 bf16 = 6.29 MB
    float* Hws  = (float*)((char*)d_ws + (size_t)B_ * N_ * 192 * 2); // 4.19 MB

    ggnn_pre<<<dim3(2048), dim3(256), 0, stream>>>(
        node_slice, type_slice, emb_table, type_table,
        W_in, Wr, br, Wz, bz, Wt, bt, NTbf, Hws);

    ggnn_main<<<dim3(B_), dim3(256), 0, stream>>>(
        rel_matrix, input_len, distance, rel_table,
        W_in, b_in, Wr, Wz, Wt, W_co, b_co,
        W1, b1, W2, b2, W3, b3, W4, b4,
        NTbf, Hws, (float*)d_out);
}

// Round 6
// 460.188 us; speedup vs baseline: 1.1882x; 1.0002x over previous
//
#include <hip/hip_runtime.h>
#include <hip/hip_bf16.h>

// GGNN fused scan v9. B=128, N=128, E=64, T=32, R=32.
// ggnn_pre: v2 (2048 blocks x 8 rows, per-lane vector gather).
// ggnn_main v9: 512 threads (8 waves), 3 barriers/step, dual wave-groups:
//   A = waves 0-3 (gates; no H state):
//     S1: w0 r-gate, w1 z-gate (each computes dis0 = pmax-combine + patch)
//     S2: w2 t-gate+upd+stats | w3 part1 = (1-z)dis0 @ Win
//     S3: w3 part2 = (z*hh) @ Win; updH = part1+part2
//   B = waves 4-7 (H owners, 32 j each, e-pair layout):
//     computes pmax for step i+1 DURING step i (col j==i masked, patched by
//     A next step from updH), spread across S1/S2/S3; merge row i-1 at S1.
//   2 waves/SIMD -> dependent-latency interleave (was 1 wave/SIMD).
//   Raw s_barrier+lgkmcnt only; NT prefetch stays in flight.

#define B_ 128
#define N_ 128

typedef unsigned short u16;
typedef unsigned int u32;

__device__ __forceinline__ float b2f(u16 u) {
    union { u32 i; float f; } c; c.i = ((u32)u) << 16; return c.f;
}
__device__ __forceinline__ u16 f2b(float f) {
    union { float f; u32 i; } c; c.f = f;
    u32 u = c.i;
    return (u16)((u + 0x7fffu + ((u >> 16) & 1u)) >> 16);
}
__device__ __forceinline__ float sigmoidf_(float x) { return 1.0f / (1.0f + __expf(-x)); }
__device__ __forceinline__ float tanhf_(float x) { return 1.0f - 2.0f / (__expf(2.0f * x) + 1.0f); }
__device__ __forceinline__ float rlane(float v, int k) {
    return __int_as_float(__builtin_amdgcn_readlane(__float_as_int(v), k));
}
#define BARRIER() asm volatile("s_waitcnt lgkmcnt(0)\n\ts_barrier" ::: "memory")

__device__ __forceinline__ float rmv(float v, const float (&wc)[64], float a0i) {
    float a0 = a0i, a1 = 0.f, a2 = 0.f, a3 = 0.f;
    #pragma unroll
    for (int k = 0; k < 64; k += 4) {
        a0 += rlane(v, k)     * wc[k];
        a1 += rlane(v, k + 1) * wc[k + 1];
        a2 += rlane(v, k + 2) * wc[k + 2];
        a3 += rlane(v, k + 3) * wc[k + 3];
    }
    return (a0 + a1) + (a2 + a3);
}

// partial max over rvw groups [G0,G1), pair layout. Col S masked (-1 = none).
template<int G0, int G1>
__device__ __forceinline__ void chunk_part(
    const u32 (&rvw)[4], const u32* __restrict__ relW32p,
    const float (&dregp)[16], int S, int jb, int p,
    const float (&hA)[16], const float (&hB)[16], float& mA, float& mB)
{
    const int Sw = S >> 2;
    const u32 km = ~(0xFFu << ((S & 3) * 8));
    #pragma unroll
    for (int g = G0; g < G1; ++g) {
        u32 d = rvw[g];
        d = ((jb >> 2) + g == Sw) ? (d & km) : d;
        #pragma unroll
        for (int bb = 0; bb < 4; ++bb) {
            const int jj = 4 * g + bb;
            u32 rr = (d >> (bb * 8)) & 255u;
            u32 pr = relW32p[(rr << 5) + p];
            float rwbA = __uint_as_float(pr << 16);
            float rwbB = __uint_as_float(pr & 0xffff0000u);
            float dd = dregp[jj];
            float sA = fmaxf(hA[jj] + rwbA, 0.f) * dd;
            float sB = fmaxf(hB[jj] + rwbB, 0.f) * dd;
            mA = rr ? fmaxf(mA, sA) : mA;
            mB = rr ? fmaxf(mB, sB) : mB;
        }
    }
}

// pair-layout partial -> lane-e max, written to pmax slot
__device__ __forceinline__ void combine_write(float mA, float mB, int e,
                                              float* __restrict__ slotbase)
{
    int s0 = (e >> 1) << 2, s1 = ((e >> 1) + 32) << 2;
    float v0a = __int_as_float(__builtin_amdgcn_ds_bpermute(s0, __float_as_int(mA)));
    float v0b = __int_as_float(__builtin_amdgcn_ds_bpermute(s0, __float_as_int(mB)));
    float v1a = __int_as_float(__builtin_amdgcn_ds_bpermute(s1, __float_as_int(mA)));
    float v1b = __int_as_float(__builtin_amdgcn_ds_bpermute(s1, __float_as_int(mB)));
    float c0 = (e & 1) ? v0b : v0a;
    float c1 = (e & 1) ? v1b : v1a;
    slotbase[e] = fmaxf(c0, c1);
}

// dis0 = combine(4 pmax slots) + fresh col(i-1) patch, NEGINF->0
__device__ __forceinline__ float compute_dis0(
    const float* __restrict__ pm, const float* __restrict__ updH_,
    const unsigned char* __restrict__ relL_, const u32* __restrict__ relW32_,
    const float* __restrict__ disc_, int i, int e)
{
    float mm = fmaxf(fmaxf(pm[e], pm[64 + e]), fmaxf(pm[128 + e], pm[192 + e]));
    if (i > 0) {
        int rb = relL_[i * N_ + (i - 1)];
        if (rb) {
            u32 pr = relW32_[(rb << 5) + (e >> 1)];
            float rwb = __uint_as_float((e & 1) ? (pr & 0xffff0000u) : (pr << 16));
            mm = fmaxf(mm, fmaxf(updH_[e] + rwb, 0.f) * disc_[i - 1]);
        }
    }
    return (mm == -__builtin_inff()) ? 0.f : mm;
}

// ---------------- precompute kernel v2 (unchanged) ----------------
__global__ __launch_bounds__(256, 2) void ggnn_pre(
    const int* __restrict__ node_slice, const int* __restrict__ type_slice,
    const float* __restrict__ emb_table, const float* __restrict__ type_table,
    const float* __restrict__ W_in,
    const float* __restrict__ Wr, const float* __restrict__ br,
    const float* __restrict__ Wz, const float* __restrict__ bz,
    const float* __restrict__ Wt, const float* __restrict__ bt,
    u16* __restrict__ NTbf, float* __restrict__ Hws)
{
    const int b  = blockIdx.x >> 4;
    const int i0 = (blockIdx.x & 15) * 8;
    const int t = threadIdx.x;
    const int w = t >> 6;
    const int e = t & 63;

    float wc[96];
    float bias = 0.f;
    if (w < 3) {
        const float* W  = (w == 0) ? Wr : (w == 1) ? Wz : Wt;
        const float* bb = (w == 0) ? br : (w == 1) ? bz : bt;
        bias = bb[e];
        #pragma unroll
        for (int k = 0; k < 96; ++k) wc[k] = W[k * 64 + e];
    } else {
        #pragma unroll
        for (int k = 0; k < 64; ++k) wc[k] = W_in[k * 64 + e];
        #pragma unroll
        for (int k = 64; k < 96; ++k) wc[k] = 0.f;
    }

    int nodes[8], typs[8];
    #pragma unroll
    for (int r = 0; r < 8; ++r) {
        nodes[r] = node_slice[b * N_ + i0 + r];
        typs[r]  = type_slice[b * N_ + i0 + r];
    }

    float xa[8], xb[8];
    #pragma unroll
    for (int r = 0; r < 8; ++r) {
        const float* pa = (e < 32)
            ? (type_table + (size_t)typs[r] * 32 + e)
            : (emb_table + (size_t)nodes[r] * 64 + (e - 32));
        xa[r] = *pa;
        xb[r] = emb_table[(size_t)nodes[r] * 64 + 32 + (e & 31)];
    }

    #pragma unroll
    for (int r = 0; r < 8; ++r) {
        if (w < 3) {
            float a0 = bias, a1 = 0.f, a2 = 0.f, a3 = 0.f;
            #pragma unroll
            for (int k = 0; k < 32; k += 4) {
                a0 += rlane(xa[r], k)     * wc[k];
                a1 += rlane(xa[r], k + 1) * wc[k + 1];
                a2 += rlane(xa[r], k + 2) * wc[k + 2];
                a3 += rlane(xa[r], k + 3) * wc[k + 3];
            }
            #pragma unroll
            for (int k = 0; k < 32; k += 4) {
                a0 += rlane(xa[r], 32 + k)     * wc[32 + k];
                a1 += rlane(xa[r], 32 + k + 1) * wc[32 + k + 1];
                a2 += rlane(xa[r], 32 + k + 2) * wc[32 + k + 2];
                a3 += rlane(xa[r], 32 + k + 3) * wc[32 + k + 3];
            }
            #pragma unroll
            for (int k = 32; k < 64; k += 4) {
                a0 += rlane(xb[r], k - 32) * wc[32 + k];
                a1 += rlane(xb[r], k - 31) * wc[32 + k + 1];
                a2 += rlane(xb[r], k - 30) * wc[32 + k + 2];
                a3 += rlane(xb[r], k - 29) * wc[32 + k + 3];
            }
            NTbf[(size_t)(b * N_ + i0 + r) * 192 + w * 64 + e] =
                f2b((a0 + a1) + (a2 + a3));
        } else {
            float a0 = 0.f, a1 = 0.f, a2 = 0.f, a3 = 0.f;
            #pragma unroll
            for (int k = 0; k < 32; k += 4) {
                a0 += rlane(xa[r], 32 + k)     * wc[k];
                a1 += rlane(xa[r], 32 + k + 1) * wc[k + 1];
                a2 += rlane(xa[r], 32 + k + 2) * wc[k + 2];
                a3 += rlane(xa[r], 32 + k + 3) * wc[k + 3];
            }
            #pragma unroll
            for (int k = 32; k < 64; k += 4) {
                a0 += rlane(xb[r], k - 32) * wc[k];
                a1 += rlane(xb[r], k - 31) * wc[k + 1];
                a2 += rlane(xb[r], k - 30) * wc[k + 2];
                a3 += rlane(xb[r], k - 29) * wc[k + 3];
            }
            Hws[(size_t)(b * N_ + i0 + r) * 64 + e] = (a0 + a1) + (a2 + a3);
        }
    }
}

// ---------------- main scan kernel v9 ----------------
__global__ __launch_bounds__(512, 1) void ggnn_main(
    const int* __restrict__ rel_matrix,
    const int* __restrict__ input_length, const float* __restrict__ distance,
    const float* __restrict__ rel_table,
    const float* __restrict__ W_in, const float* __restrict__ b_in,
    const float* __restrict__ Wr, const float* __restrict__ Wz, const float* __restrict__ Wt,
    const float* __restrict__ W_co, const float* __restrict__ b_co,
    const float* __restrict__ W1, const float* __restrict__ b1,
    const float* __restrict__ W2, const float* __restrict__ b2,
    const float* __restrict__ W3, const float* __restrict__ b3,
    const float* __restrict__ W4, const float* __restrict__ b4,
    const u16* __restrict__ NTbf, const float* __restrict__ Hws,
    float* __restrict__ out)
{
    __shared__ __align__(16) u32   relW32[51 * 32];       // 6.4 KB, [r][e-pair]
    __shared__ __align__(16) unsigned char relL[128 * 128]; // 16 KB, len-masked
    __shared__ __align__(16) float disc[N_];
    __shared__ __align__(16) float pmax[2][256];          // parity x 4 slots
    __shared__ __align__(16) float r_row[64], z_row[64], v2row[64], updH[64];
    __shared__ __align__(16) float userrow[64], itemrow[64], submrow[64];
    __shared__ __align__(16) float temp[192];
    __shared__ float h1[128];
    __shared__ float h2v[64];
    __shared__ float h3v[32];

    const int b = blockIdx.x;
    const int t = threadIdx.x;
    const int w = t >> 6;          // 0..7
    const int e = t & 63;
    const int p = e & 31;
    const int half = e >> 5;
    const int len = input_length[b];
    const float NEGINF = -__builtin_inff();

    // B-group H ownership: wave 4+q owns j in [32q, 32q+32)
    const int jbase = (w >= 4) ? ((w - 4) * 32 + half * 16) : 0;

    // ---- staging ----
    if (t < N_) disc[t] = -0.1f * distance[b * N_ + t];

    {   // rel_matrix -> u8, len-masked
        const int4* src = (const int4*)(rel_matrix + b * N_ * N_);
        u32* dst = (u32*)relL;
        for (int c = t; c < 4096; c += 512) {
            int4 v = src[c];
            int j = (c * 4) & 127;
            u32 pk = (u32)((j + 0 < len && v.x) ? v.x : 0)
                   | ((u32)((j + 1 < len && v.y) ? v.y : 0) << 8)
                   | ((u32)((j + 2 < len && v.z) ? v.z : 0) << 16)
                   | ((u32)((j + 3 < len && v.w) ? v.w : 0) << 24);
            dst[c] = pk;
        }
    }
    for (int idx = t; idx < 51 * 32; idx += 512) {        // relW32 = b_in + rel@W_in_bot
        int r = idx >> 5, pp = idx & 31;
        float aA = b_in[2 * pp], aB = b_in[2 * pp + 1];
        #pragma unroll
        for (int k = 0; k < 32; ++k) {
            float rt = rel_table[r * 32 + k];
            aA += rt * W_in[(64 + k) * 64 + 2 * pp];
            aB += rt * W_in[(64 + k) * 64 + 2 * pp + 1];
        }
        relW32[idx] = (u32)f2b(aA) | ((u32)f2b(aB) << 16);
    }

    // A: per-wave weight column. w0=Wr_bot, w1=Wz_bot, w2=Wt_bot, w3=W_in_top
    float wcol[64];
    if (w < 4) {
        const float* wsrc = (w == 0) ? (Wr + 96 * 64) : (w == 1) ? (Wz + 96 * 64)
                          : (w == 2) ? (Wt + 96 * 64) : W_in;
        #pragma unroll
        for (int k = 0; k < 64; ++k) wcol[k] = wsrc[k * 64 + e];
    }

    // B: H registers (pair layout, 16 j per lane)
    float hA[16], hB[16];
    if (w >= 4) {
        const float2* H2 = (const float2*)(Hws + (size_t)b * N_ * 64);
        #pragma unroll
        for (int jj = 0; jj < 16; ++jj) {
            float2 v = H2[(jbase + jj) * 32 + p];
            hA[jj] = v.x; hB[jj] = v.y;
        }
    }

    // NT prefetch (step 0): A waves 0-2
    const u16* NTb = NTbf + (size_t)b * N_ * 192;
    u16 ntc = 0;
    if (w < 3) ntc = NTb[w * 64 + e];
    float user_r = 0.f, item_r = 0.f, subm_r = NEGINF;

    __syncthreads();                                      // staging visible

    // B: disc regs + prologue max for step 0 (unmasked)
    float dregp[16];
    if (w >= 4) {
        #pragma unroll
        for (int jj = 0; jj < 16; ++jj) dregp[jj] = disc[jbase + jj];
        uint4 rvv = *(const uint4*)(relL + jbase);
        u32 rv0[4] = {rvv.x, rvv.y, rvv.z, rvv.w};
        float mA = NEGINF, mB = NEGINF;
        chunk_part<0, 4>(rv0, relW32, dregp, -1, jbase, p, hA, hB, mA, mB);
        combine_write(mA, mB, e, pmax[0] + ((w - 4) << 6));
    }
    __syncthreads();                                      // pmax[0] ready

    // ---- scan ----
    for (int i = 0; i < len; ++i) {
        const int par = i & 1;
        const bool doPart = (i + 1 < len);
        u16 ntp = 0;
        u32 rvw[4] = {0, 0, 0, 0};
        float mA = NEGINF, mB = NEGINF;
        float part1 = 0.f;

        // ---- S1 ----
        if (w < 4) {
            if (w < 3) ntp = NTb[((i + 1) & 127) * 192 + w * 64 + e];
            if (w < 2) {
                float dis0 = compute_dis0(pmax[par], updH, relL, relW32, disc, i, e);
                float g = sigmoidf_(rmv(dis0, wcol, b2f(ntc)));
                if (w == 0) r_row[e] = g; else z_row[e] = g;
            }
        } else {
            if (i > 0) {                                   // merge row i-1
                const int prev = i - 1;
                if (w == 4 + (prev >> 5)) {
                    float2 u = ((const float2*)updH)[p];
                    const bool hm = (half == ((prev >> 4) & 1));
                    const int oj = prev & 15;
                    #pragma unroll
                    for (int jj = 0; jj < 16; ++jj) if (jj == oj) {
                        hA[jj] = hm ? u.x : hA[jj];
                        hB[jj] = hm ? u.y : hB[jj];
                    }
                }
            }
            if (doPart) {
                uint4 rvv = *(const uint4*)(relL + (i + 1) * N_ + jbase);
                rvw[0] = rvv.x; rvw[1] = rvv.y; rvw[2] = rvv.z; rvw[3] = rvv.w;
                chunk_part<0, 2>(rvw, relW32, dregp, i, jbase, p, hA, hB, mA, mB);
            }
        }
        BARRIER();                                        // S1 end

        // ---- S2 ----
        if (w == 2) {
            float dis0 = compute_dis0(pmax[par], updH, relL, relW32, disc, i, e);
            float rdp = r_row[e] * dis0;
            float hh = tanhf_(rmv(rdp, wcol, b2f(ntc)));
            float z = z_row[e];
            float zh = z * hh;
            float upd = (1.f - z) * dis0 + zh;
            v2row[e] = zh;
            if (i == 0) user_r = upd;
            subm_r = fmaxf(subm_r, upd);
            item_r = upd;
        } else if (w == 3) {
            float dis0 = compute_dis0(pmax[par], updH, relL, relW32, disc, i, e);
            part1 = rmv((1.f - z_row[e]) * dis0, wcol, 0.f);
        } else if (w >= 4 && doPart) {
            chunk_part<2, 3>(rvw, relW32, dregp, i, jbase, p, hA, hB, mA, mB);
        }
        BARRIER();                                        // S2 end

        // ---- S3 ----
        if (w == 3) {
            float pt2 = rmv(v2row[e], wcol, 0.f);
            updH[e] = part1 + pt2;
        } else if (w >= 4 && doPart) {
            chunk_part<3, 4>(rvw, relW32, dregp, i, jbase, p, hA, hB, mA, mB);
            combine_write(mA, mB, e, pmax[par ^ 1] + ((w - 4) << 6));
        }
        if (w < 3) ntc = ntp;
        BARRIER();                                        // step end
    }

    if (w == 2) { userrow[e] = user_r; itemrow[e] = item_r; submrow[e] = subm_r; }
    __syncthreads();

    // ---- epilogue ----
    if (t < 128) {
        const int half2 = t >> 6;               // 0: ua*user, 1: ia*item
        const float* row = (half2 == 0) ? userrow : itemrow;
        float acc = b_co[e];
        #pragma unroll
        for (int k = 0; k < 64; ++k) acc += row[k] * W_co[k * 64 + e];
        #pragma unroll
        for (int k = 0; k < 64; ++k) acc += submrow[k] * W_co[(64 + k) * 64 + e];
        float act = fmaxf(acc, 0.f);
        temp[half2 * 128 + e] = act * row[e];
    } else if (t < 192) {
        temp[64 + (t - 128)] = submrow[t - 128];
    }
    __syncthreads();

    if (t < 128) {
        float acc = b1[t];
        for (int k = 0; k < 192; ++k) acc += temp[k] * W1[k * 128 + t];
        h1[t] = fmaxf(acc, 0.f);
    }
    __syncthreads();
    if (t < 64) {
        float acc = b2[t];
        for (int k = 0; k < 128; ++k) acc += h1[k] * W2[k * 64 + t];
        h2v[t] = fmaxf(acc, 0.f);
    }
    __syncthreads();
    if (t < 32) {
        float acc = b3[t];
        for (int k = 0; k < 64; ++k) acc += h2v[k] * W3[k * 32 + t];
        h3v[t] = fmaxf(acc, 0.f);
    }
    __syncthreads();
    if (t == 0) {
        float acc = b4[0];
        for (int k = 0; k < 32; ++k) acc += h3v[k] * W4[k];
        out[b] = sigmoidf_(acc);
    }
}

extern "C" void kernel_launch(void* const* d_in, const int* in_sizes, int n_in,
                              void* d_out, int out_size, void* d_ws, size_t ws_size,
                              hipStream_t stream)
{
    const int*   node_slice = (const int*)d_in[0];
    const int*   type_slice = (const int*)d_in[1];
    const float* distance   = (const float*)d_in[2];
    const int*   rel_matrix = (const int*)d_in[3];
    const int*   input_len  = (const int*)d_in[4];
    // d_in[5] = isBatch (ignored)
    const float* emb_table  = (const float*)d_in[6];
    const float* type_table = (const float*)d_in[7];
    const float* rel_table  = (const float*)d_in[8];
    const float* W_in = (const float*)d_in[9];  const float* b_in = (const float*)d_in[10];
    const float* Wr   = (const float*)d_in[11]; const float* br   = (const float*)d_in[12];
    const float* Wz   = (const float*)d_in[13]; const float* bz   = (const float*)d_in[14];
    const float* Wt   = (const float*)d_in[15]; const float* bt   = (const float*)d_in[16];
    const float* W_co = (const float*)d_in[17]; const float* b_co = (const float*)d_in[18];
    const float* W1   = (const float*)d_in[19]; const float* b1   = (const float*)d_in[20];
    const float* W2   = (const float*)d_in[21]; const float* b2   = (const float*)d_in[22];
    const float* W3   = (const float*)d_in[23]; const float* b3   = (const float*)d_in[24];
    const float* W4   = (const float*)d_in[25]; const float* b4   = (const float*)d_in[26];

    u16*   NTbf = (u16*)d_ws;                            // 128*128*192 bf16 = 6.29 MB
    float* Hws  = (float*)((char*)d_ws + (size_t)B_ * N_ * 192 * 2); // 4.19 MB

    ggnn_pre<<<dim3(2048), dim3(256), 0, stream>>>(
        node_slice, type_slice, emb_table, type_table,
        W_in, Wr, br, Wz, bz, Wt, bt, NTbf, Hws);

    ggnn_main<<<dim3(B_), dim3(512), 0, stream>>>(
        rel_matrix, input_len, distance, rel_table,
        W_in, b_in, Wr, Wz, Wt, W_co, b_co,
        W1, b1, W2, b2, W3, b3, W4, b4,
        NTbf, Hws, (float*)d_out);
}

// Round 7
// 377.804 us; speedup vs baseline: 1.4473x; 1.2181x over previous
//
#include <hip/hip_runtime.h>
#include <hip/hip_bf16.h>

// GGNN fused scan v10. B=128, N=128, E=64, T=32, R=32.
// ggnn_pre: v2 (2048 blocks x 8 rows, per-lane vector gather).
// ggnn_main v10: ONE barrier per step. 4 waves, two divergent loop nests
//   with matched barrier counts:
//   - wave 3 ("GRU wave"): holds ALL FOUR weight columns in regs (Wr/Wz/Wt
//     bottom + W_in top = 256 VGPR; 1 wave/SIMD -> 512 cap). Whole chain
//     register-resident: dis0 (pmax combine + fresh-col patch from OWN regs)
//     -> combined r+z readlane loop -> t loop -> upd -> H loop -> updH write.
//     No LDS turnaround inside the chain.
//   - waves 0-2 (H owners: j 0-47 / 48-95 / 96-127, e-pair layout):
//     merge row i-1 from updH, compute pmax for step i+1 (col i masked),
//     write pmax[par^1]. Fully concurrent with w3's chain.
//   Cross-wave traffic per step: pmax (B->w3, 1 step ahead), updH (w3->B,
//   merged next step) -> single end-of-step s_barrier suffices.

#define B_ 128
#define N_ 128

typedef unsigned short u16;
typedef unsigned int u32;

__device__ __forceinline__ float b2f(u16 u) {
    union { u32 i; float f; } c; c.i = ((u32)u) << 16; return c.f;
}
__device__ __forceinline__ u16 f2b(float f) {
    union { float f; u32 i; } c; c.f = f;
    u32 u = c.i;
    return (u16)((u + 0x7fffu + ((u >> 16) & 1u)) >> 16);
}
__device__ __forceinline__ float sigmoidf_(float x) { return 1.0f / (1.0f + __expf(-x)); }
__device__ __forceinline__ float tanhf_(float x) { return 1.0f - 2.0f / (__expf(2.0f * x) + 1.0f); }
__device__ __forceinline__ float rlane(float v, int k) {
    return __int_as_float(__builtin_amdgcn_readlane(__float_as_int(v), k));
}
#define BARRIER() asm volatile("s_waitcnt lgkmcnt(0)\n\ts_barrier" ::: "memory")

// pair-layout partial -> lane-e max, written to pmax slot
__device__ __forceinline__ void combine_write(float mA, float mB, int e,
                                              float* __restrict__ slotbase)
{
    int s0 = (e >> 1) << 2, s1 = ((e >> 1) + 32) << 2;
    float v0a = __int_as_float(__builtin_amdgcn_ds_bpermute(s0, __float_as_int(mA)));
    float v0b = __int_as_float(__builtin_amdgcn_ds_bpermute(s0, __float_as_int(mB)));
    float v1a = __int_as_float(__builtin_amdgcn_ds_bpermute(s1, __float_as_int(mA)));
    float v1b = __int_as_float(__builtin_amdgcn_ds_bpermute(s1, __float_as_int(mB)));
    float c0 = (e & 1) ? v0b : v0a;
    float c1 = (e & 1) ? v1b : v1a;
    slotbase[e] = fmaxf(c0, c1);
}

// B-wave scan loop: NJ = per-half j count (24 for w0/w1, 16 for w2)
template<int NJ>
__device__ __forceinline__ void bloop(
    int b, int w, int e, int p, int half, int len,
    const float* __restrict__ Hws,
    const unsigned char* __restrict__ relL,
    const u32* __restrict__ relW32,
    const float* __restrict__ disc,
    float* __restrict__ pmaxF,            // [2*192]
    const float* __restrict__ updH)
{
    const float NEGINF = -__builtin_inff();
    const int base = w * 48 + half * NJ;

    float hA[NJ], hB[NJ], dreg[NJ];
    {
        const float2* H2 = (const float2*)(Hws + (size_t)b * N_ * 64);
        #pragma unroll
        for (int jj = 0; jj < NJ; ++jj) {
            float2 v = H2[(base + jj) * 32 + p];
            hA[jj] = v.x; hB[jj] = v.y;
            dreg[jj] = disc[base + jj];
        }
    }

    // prologue: pmax[0] over all j (unmasked)
    {
        float mA = NEGINF, mB = NEGINF;
        const u32* rw = (const u32*)(relL + base);
        #pragma unroll
        for (int g = 0; g < NJ / 4; ++g) {
            u32 d = rw[g];
            #pragma unroll
            for (int bb = 0; bb < 4; ++bb) {
                const int jj = 4 * g + bb;
                u32 rr = (d >> (bb * 8)) & 255u;
                u32 pr = relW32[(rr << 5) + p];
                float rwbA = __uint_as_float(pr << 16);
                float rwbB = __uint_as_float(pr & 0xffff0000u);
                float dd = dreg[jj];
                float sA = fmaxf(hA[jj] + rwbA, 0.f) * dd;
                float sB = fmaxf(hB[jj] + rwbB, 0.f) * dd;
                mA = rr ? fmaxf(mA, sA) : mA;
                mB = rr ? fmaxf(mB, sB) : mB;
            }
        }
        combine_write(mA, mB, e, pmaxF + (w << 6));
    }
    BARRIER();                                            // prologue barrier

    for (int i = 0; i < len; ++i) {
        if (i > 0) {                                      // merge row i-1
            const int prev = i - 1;
            const int ow = (prev < 48) ? 0 : (prev < 96) ? 1 : 2;
            if (w == ow) {
                float2 u = ((const float2*)updH)[p];
                const int off = prev - ow * 48;
                const int hs = off / NJ;
                const int oj = off % NJ;
                if (half == hs) {
                    #pragma unroll
                    for (int jj = 0; jj < NJ; ++jj) if (jj == oj) {
                        hA[jj] = u.x; hB[jj] = u.y;
                    }
                }
            }
        }
        if (i + 1 < len) {                                // pmax for step i+1
            float mA = NEGINF, mB = NEGINF;
            const u32* rw = (const u32*)(relL + (i + 1) * N_ + base);
            const int sl = i - base;                      // mask col i
            #pragma unroll
            for (int g = 0; g < NJ / 4; ++g) {
                u32 d = rw[g];
                #pragma unroll
                for (int bb = 0; bb < 4; ++bb) {
                    const int jj = 4 * g + bb;
                    u32 rr = (d >> (bb * 8)) & 255u;
                    rr = (jj == sl) ? 0u : rr;
                    u32 pr = relW32[(rr << 5) + p];
                    float rwbA = __uint_as_float(pr << 16);
                    float rwbB = __uint_as_float(pr & 0xffff0000u);
                    float dd = dreg[jj];
                    float sA = fmaxf(hA[jj] + rwbA, 0.f) * dd;
                    float sB = fmaxf(hB[jj] + rwbB, 0.f) * dd;
                    mA = rr ? fmaxf(mA, sA) : mA;
                    mB = rr ? fmaxf(mB, sB) : mB;
                }
            }
            combine_write(mA, mB, e, pmaxF + ((i & 1) ^ 1) * 192 + (w << 6));
        }
        BARRIER();                                        // step barrier
    }
}

// ---------------- precompute kernel v2 (unchanged) ----------------
__global__ __launch_bounds__(256, 2) void ggnn_pre(
    const int* __restrict__ node_slice, const int* __restrict__ type_slice,
    const float* __restrict__ emb_table, const float* __restrict__ type_table,
    const float* __restrict__ W_in,
    const float* __restrict__ Wr, const float* __restrict__ br,
    const float* __restrict__ Wz, const float* __restrict__ bz,
    const float* __restrict__ Wt, const float* __restrict__ bt,
    u16* __restrict__ NTbf, float* __restrict__ Hws)
{
    const int b  = blockIdx.x >> 4;
    const int i0 = (blockIdx.x & 15) * 8;
    const int t = threadIdx.x;
    const int w = t >> 6;
    const int e = t & 63;

    float wc[96];
    float bias = 0.f;
    if (w < 3) {
        const float* W  = (w == 0) ? Wr : (w == 1) ? Wz : Wt;
        const float* bb = (w == 0) ? br : (w == 1) ? bz : bt;
        bias = bb[e];
        #pragma unroll
        for (int k = 0; k < 96; ++k) wc[k] = W[k * 64 + e];
    } else {
        #pragma unroll
        for (int k = 0; k < 64; ++k) wc[k] = W_in[k * 64 + e];
        #pragma unroll
        for (int k = 64; k < 96; ++k) wc[k] = 0.f;
    }

    int nodes[8], typs[8];
    #pragma unroll
    for (int r = 0; r < 8; ++r) {
        nodes[r] = node_slice[b * N_ + i0 + r];
        typs[r]  = type_slice[b * N_ + i0 + r];
    }

    float xa[8], xb[8];
    #pragma unroll
    for (int r = 0; r < 8; ++r) {
        const float* pa = (e < 32)
            ? (type_table + (size_t)typs[r] * 32 + e)
            : (emb_table + (size_t)nodes[r] * 64 + (e - 32));
        xa[r] = *pa;
        xb[r] = emb_table[(size_t)nodes[r] * 64 + 32 + (e & 31)];
    }

    #pragma unroll
    for (int r = 0; r < 8; ++r) {
        if (w < 3) {
            float a0 = bias, a1 = 0.f, a2 = 0.f, a3 = 0.f;
            #pragma unroll
            for (int k = 0; k < 32; k += 4) {
                a0 += rlane(xa[r], k)     * wc[k];
                a1 += rlane(xa[r], k + 1) * wc[k + 1];
                a2 += rlane(xa[r], k + 2) * wc[k + 2];
                a3 += rlane(xa[r], k + 3) * wc[k + 3];
            }
            #pragma unroll
            for (int k = 0; k < 32; k += 4) {
                a0 += rlane(xa[r], 32 + k)     * wc[32 + k];
                a1 += rlane(xa[r], 32 + k + 1) * wc[32 + k + 1];
                a2 += rlane(xa[r], 32 + k + 2) * wc[32 + k + 2];
                a3 += rlane(xa[r], 32 + k + 3) * wc[32 + k + 3];
            }
            #pragma unroll
            for (int k = 32; k < 64; k += 4) {
                a0 += rlane(xb[r], k - 32) * wc[32 + k];
                a1 += rlane(xb[r], k - 31) * wc[32 + k + 1];
                a2 += rlane(xb[r], k - 30) * wc[32 + k + 2];
                a3 += rlane(xb[r], k - 29) * wc[32 + k + 3];
            }
            NTbf[(size_t)(b * N_ + i0 + r) * 192 + w * 64 + e] =
                f2b((a0 + a1) + (a2 + a3));
        } else {
            float a0 = 0.f, a1 = 0.f, a2 = 0.f, a3 = 0.f;
            #pragma unroll
            for (int k = 0; k < 32; k += 4) {
                a0 += rlane(xa[r], 32 + k)     * wc[k];
                a1 += rlane(xa[r], 32 + k + 1) * wc[k + 1];
                a2 += rlane(xa[r], 32 + k + 2) * wc[k + 2];
                a3 += rlane(xa[r], 32 + k + 3) * wc[k + 3];
            }
            #pragma unroll
            for (int k = 32; k < 64; k += 4) {
                a0 += rlane(xb[r], k - 32) * wc[k];
                a1 += rlane(xb[r], k - 31) * wc[k + 1];
                a2 += rlane(xb[r], k - 30) * wc[k + 2];
                a3 += rlane(xb[r], k - 29) * wc[k + 3];
            }
            Hws[(size_t)(b * N_ + i0 + r) * 64 + e] = (a0 + a1) + (a2 + a3);
        }
    }
}

// ---------------- main scan kernel v10 ----------------
__global__ __launch_bounds__(256, 1) void ggnn_main(
    const int* __restrict__ rel_matrix,
    const int* __restrict__ input_length, const float* __restrict__ distance,
    const float* __restrict__ rel_table,
    const float* __restrict__ W_in, const float* __restrict__ b_in,
    const float* __restrict__ Wr, const float* __restrict__ Wz, const float* __restrict__ Wt,
    const float* __restrict__ W_co, const float* __restrict__ b_co,
    const float* __restrict__ W1, const float* __restrict__ b1,
    const float* __restrict__ W2, const float* __restrict__ b2,
    const float* __restrict__ W3, const float* __restrict__ b3,
    const float* __restrict__ W4, const float* __restrict__ b4,
    const u16* __restrict__ NTbf, const float* __restrict__ Hws,
    float* __restrict__ out)
{
    __shared__ __align__(16) u32   relW32[51 * 32];       // 6.4 KB, [r][e-pair]
    __shared__ __align__(16) unsigned char relL[128 * 128]; // 16 KB, len-masked
    __shared__ __align__(16) float disc[N_];
    __shared__ __align__(16) float pmaxF[2 * 192];        // parity x 3 slots
    __shared__ __align__(16) float updH[64];
    __shared__ __align__(16) float userrow[64], itemrow[64], submrow[64];
    __shared__ __align__(16) float temp[192];
    __shared__ float h1[128];
    __shared__ float h2v[64];
    __shared__ float h3v[32];

    const int b = blockIdx.x;
    const int t = threadIdx.x;
    const int w = t >> 6;          // 0..3
    const int e = t & 63;
    const int p = e & 31;
    const int half = e >> 5;
    const int len = input_length[b];
    const float NEGINF = -__builtin_inff();

    // ---- staging (all 256 threads) ----
    if (t < N_) disc[t] = -0.1f * distance[b * N_ + t];

    {   // rel_matrix -> u8, len-masked
        const int4* src = (const int4*)(rel_matrix + b * N_ * N_);
        u32* dst = (u32*)relL;
        for (int c = t; c < 4096; c += 256) {
            int4 v = src[c];
            int j = (c * 4) & 127;
            u32 pk = (u32)((j + 0 < len && v.x) ? v.x : 0)
                   | ((u32)((j + 1 < len && v.y) ? v.y : 0) << 8)
                   | ((u32)((j + 2 < len && v.z) ? v.z : 0) << 16)
                   | ((u32)((j + 3 < len && v.w) ? v.w : 0) << 24);
            dst[c] = pk;
        }
    }
    for (int idx = t; idx < 51 * 32; idx += 256) {        // relW32 = b_in + rel@W_in_bot
        int r = idx >> 5, pp = idx & 31;
        float aA = b_in[2 * pp], aB = b_in[2 * pp + 1];
        #pragma unroll
        for (int k = 0; k < 32; ++k) {
            float rt = rel_table[r * 32 + k];
            aA += rt * W_in[(64 + k) * 64 + 2 * pp];
            aB += rt * W_in[(64 + k) * 64 + 2 * pp + 1];
        }
        relW32[idx] = (u32)f2b(aA) | ((u32)f2b(aB) << 16);
    }
    __syncthreads();                                      // staging visible

    if (w < 3) {
        // ---- B-waves: H owners + pmax producer ----
        if (w == 2) bloop<16>(b, w, e, p, half, len, Hws, relL, relW32,
                              disc, pmaxF, updH);
        else        bloop<24>(b, w, e, p, half, len, Hws, relL, relW32,
                              disc, pmaxF, updH);
    } else {
        // ---- GRU wave: full chain in registers ----
        float wcr[64], wcz[64], wct[64], wcH[64];
        #pragma unroll
        for (int k = 0; k < 64; ++k) {
            wcr[k] = Wr[(96 + k) * 64 + e];
            wcz[k] = Wz[(96 + k) * 64 + e];
            wct[k] = Wt[(96 + k) * 64 + e];
            wcH[k] = W_in[k * 64 + e];
        }
        const u16* NTb = NTbf + (size_t)b * N_ * 192;
        u16 ncr = NTb[e], ncz = NTb[64 + e], nct = NTb[128 + e];
        float uH = 0.f;
        float user_r = 0.f, item_r = 0.f, subm_r = NEGINF;
        BARRIER();                                        // prologue barrier

        for (int i = 0; i < len; ++i) {
            const float* pm = pmaxF + (i & 1) * 192;
            float mm = fmaxf(fmaxf(pm[e], pm[64 + e]), pm[128 + e]);
            if (i > 0) {
                int rb = relL[i * N_ + (i - 1)];          // uniform broadcast
                if (rb) {
                    u32 pr = relW32[(rb << 5) + (e >> 1)];
                    float rwb = __uint_as_float((e & 1) ? (pr & 0xffff0000u)
                                                        : (pr << 16));
                    mm = fmaxf(mm, fmaxf(uH + rwb, 0.f) * disc[i - 1]);
                }
            }
            float dis0 = (mm == NEGINF) ? 0.f : mm;

            // NT prefetch for step i+1
            const int nrow = ((i + 1) & 127) * 192;
            u16 npr = NTb[nrow + e], npz = NTb[nrow + 64 + e],
                npt = NTb[nrow + 128 + e];

            // combined r,z matvec (one readlane feeds both)
            float ra0 = b2f(ncr), ra1 = 0.f, ra2 = 0.f, ra3 = 0.f;
            float za0 = b2f(ncz), za1 = 0.f, za2 = 0.f, za3 = 0.f;
            #pragma unroll
            for (int k = 0; k < 64; k += 4) {
                float s0 = rlane(dis0, k),     s1 = rlane(dis0, k + 1);
                float s2 = rlane(dis0, k + 2), s3 = rlane(dis0, k + 3);
                ra0 += s0 * wcr[k];     za0 += s0 * wcz[k];
                ra1 += s1 * wcr[k + 1]; za1 += s1 * wcz[k + 1];
                ra2 += s2 * wcr[k + 2]; za2 += s2 * wcz[k + 2];
                ra3 += s3 * wcr[k + 3]; za3 += s3 * wcz[k + 3];
            }
            float r = sigmoidf_((ra0 + ra1) + (ra2 + ra3));
            float z = sigmoidf_((za0 + za1) + (za2 + za3));
            float rdp = r * dis0;

            float ta0 = b2f(nct), ta1 = 0.f, ta2 = 0.f, ta3 = 0.f;
            #pragma unroll
            for (int k = 0; k < 64; k += 4) {
                ta0 += rlane(rdp, k)     * wct[k];
                ta1 += rlane(rdp, k + 1) * wct[k + 1];
                ta2 += rlane(rdp, k + 2) * wct[k + 2];
                ta3 += rlane(rdp, k + 3) * wct[k + 3];
            }
            float hh = tanhf_((ta0 + ta1) + (ta2 + ta3));
            float upd = (1.f - z) * dis0 + z * hh;
            if (i == 0) user_r = upd;
            subm_r = fmaxf(subm_r, upd);
            item_r = upd;

            float ha0 = 0.f, ha1 = 0.f, ha2 = 0.f, ha3 = 0.f;
            #pragma unroll
            for (int k = 0; k < 64; k += 4) {
                ha0 += rlane(upd, k)     * wcH[k];
                ha1 += rlane(upd, k + 1) * wcH[k + 1];
                ha2 += rlane(upd, k + 2) * wcH[k + 2];
                ha3 += rlane(upd, k + 3) * wcH[k + 3];
            }
            uH = (ha0 + ha1) + (ha2 + ha3);
            updH[e] = uH;
            ncr = npr; ncz = npz; nct = npt;
            BARRIER();                                    // step barrier
        }
        userrow[e] = user_r; itemrow[e] = item_r; submrow[e] = subm_r;
    }
    __syncthreads();

    // ---- epilogue ----
    if (t < 128) {
        const int half2 = t >> 6;               // 0: ua*user, 1: ia*item
        const float* row = (half2 == 0) ? userrow : itemrow;
        float acc = b_co[e];
        #pragma unroll
        for (int k = 0; k < 64; ++k) acc += row[k] * W_co[k * 64 + e];
        #pragma unroll
        for (int k = 0; k < 64; ++k) acc += submrow[k] * W_co[(64 + k) * 64 + e];
        float act = fmaxf(acc, 0.f);
        temp[half2 * 128 + e] = act * row[e];
    } else if (t < 192) {
        temp[64 + (t - 128)] = submrow[t - 128];
    }
    __syncthreads();

    if (t < 128) {
        float acc = b1[t];
        for (int k = 0; k < 192; ++k) acc += temp[k] * W1[k * 128 + t];
        h1[t] = fmaxf(acc, 0.f);
    }
    __syncthreads();
    if (t < 64) {
        float acc = b2[t];
        for (int k = 0; k < 128; ++k) acc += h1[k] * W2[k * 64 + t];
        h2v[t] = fmaxf(acc, 0.f);
    }
    __syncthreads();
    if (t < 32) {
        float acc = b3[t];
        for (int k = 0; k < 64; ++k) acc += h2v[k] * W3[k * 32 + t];
        h3v[t] = fmaxf(acc, 0.f);
    }
    __syncthreads();
    if (t == 0) {
        float acc = b4[0];
        for (int k = 0; k < 32; ++k) acc += h3v[k] * W4[k];
        out[b] = sigmoidf_(acc);
    }
}

extern "C" void kernel_launch(void* const* d_in, const int* in_sizes, int n_in,
                              void* d_out, int out_size, void* d_ws, size_t ws_size,
                              hipStream_t stream)
{
    const int*   node_slice = (const int*)d_in[0];
    const int*   type_slice = (const int*)d_in[1];
    const float* distance   = (const float*)d_in[2];
    const int*   rel_matrix = (const int*)d_in[3];
    const int*   input_len  = (const int*)d_in[4];
    // d_in[5] = isBatch (ignored)
    const float* emb_table  = (const float*)d_in[6];
    const float* type_table = (const float*)d_in[7];
    const float* rel_table  = (const float*)d_in[8];
    const float* W_in = (const float*)d_in[9];  const float* b_in = (const float*)d_in[10];
    const float* Wr   = (const float*)d_in[11]; const float* br   = (const float*)d_in[12];
    const float* Wz   = (const float*)d_in[13]; const float* bz   = (const float*)d_in[14];
    const float* Wt   = (const float*)d_in[15]; const float* bt   = (const float*)d_in[16];
    const float* W_co = (const float*)d_in[17]; const float* b_co = (const float*)d_in[18];
    const float* W1   = (const float*)d_in[19]; const float* b1   = (const float*)d_in[20];
    const float* W2   = (const float*)d_in[21]; const float* b2   = (const float*)d_in[22];
    const float* W3   = (const float*)d_in[23]; const float* b3   = (const float*)d_in[24];
    const float* W4   = (const float*)d_in[25]; const float* b4   = (const float*)d_in[26];

    u16*   NTbf = (u16*)d_ws;                            // 128*128*192 bf16 = 6.29 MB
    float* Hws  = (float*)((char*)d_ws + (size_t)B_ * N_ * 192 * 2); // 4.19 MB

    ggnn_pre<<<dim3(2048), dim3(256), 0, stream>>>(
        node_slice, type_slice, emb_table, type_table,
        W_in, Wr, br, Wz, bz, Wt, bt, NTbf, Hws);

    ggnn_main<<<dim3(B_), dim3(256), 0, stream>>>(
        rel_matrix, input_len, distance, rel_table,
        W_in, b_in, Wr, Wz, Wt, W_co, b_co,
        W1, b1, W2, b2, W3, b3, W4, b4,
        NTbf, Hws, (float*)d_out);
}

// Round 8
// 365.574 us; speedup vs baseline: 1.4957x; 1.0335x over previous
//
#include <hip/hip_runtime.h>
#include <hip/hip_bf16.h>

// GGNN fused scan v11. B=128, N=128, E=64, T=32, R=32.
// ggnn_pre: v2 (unchanged).
// ggnn_main v11 (from v10's 1-barrier structure):
//   - Weight residency fix (VGPR=140 proved wc arrays were NOT resident):
//     wcr+wcz (128 f32) in regs; Wt_bot + W_in_top staged to LDS as
//     [kchunk][e] float4 (32KB) read via ds_read_b128 in t/H matvecs.
//   - Sub-diagonal of relL pre-zeroed at staging (saved to sub_l[]):
//     B-wave inner loops lose all masking logic.
//   - relW32[r=0] = packed bf16 +INF: invalid rel -> relu(h+inf)*d = -inf
//     (d<0 always) -> fmax ignores; kills cndmasks; patch is branch-free.
//   - w3 patch inputs (sub_l[i], relW32 pair, disc[i]) prefetched one full
//     step ahead (static data) -> ~240cy dependent-LDS chain off the top.

#define B_ 128
#define N_ 128

typedef unsigned short u16;
typedef unsigned int u32;

__device__ __forceinline__ float b2f(u16 u) {
    union { u32 i; float f; } c; c.i = ((u32)u) << 16; return c.f;
}
__device__ __forceinline__ u16 f2b(float f) {
    union { float f; u32 i; } c; c.f = f;
    u32 u = c.i;
    return (u16)((u + 0x7fffu + ((u >> 16) & 1u)) >> 16);
}
__device__ __forceinline__ float sigmoidf_(float x) { return 1.0f / (1.0f + __expf(-x)); }
__device__ __forceinline__ float tanhf_(float x) { return 1.0f - 2.0f / (__expf(2.0f * x) + 1.0f); }
__device__ __forceinline__ float rlane(float v, int k) {
    return __int_as_float(__builtin_amdgcn_readlane(__float_as_int(v), k));
}
#define BARRIER() asm volatile("s_waitcnt lgkmcnt(0)\n\ts_barrier" ::: "memory")

// pair-layout partial -> lane-e max, written to pmax slot
__device__ __forceinline__ void combine_write(float mA, float mB, int e,
                                              float* __restrict__ slotbase)
{
    int s0 = (e >> 1) << 2, s1 = ((e >> 1) + 32) << 2;
    float v0a = __int_as_float(__builtin_amdgcn_ds_bpermute(s0, __float_as_int(mA)));
    float v0b = __int_as_float(__builtin_amdgcn_ds_bpermute(s0, __float_as_int(mB)));
    float v1a = __int_as_float(__builtin_amdgcn_ds_bpermute(s1, __float_as_int(mA)));
    float v1b = __int_as_float(__builtin_amdgcn_ds_bpermute(s1, __float_as_int(mB)));
    float c0 = (e & 1) ? v0b : v0a;
    float c1 = (e & 1) ? v1b : v1a;
    slotbase[e] = fmaxf(c0, c1);
}

// B-wave scan loop: NJ = per-half j count (24 for w0/w1, 16 for w2).
// No masking: subdiagonal bytes are pre-zeroed; relW32[0] = +INF sentinel.
template<int NJ>
__device__ __forceinline__ void bloop(
    int b, int w, int e, int p, int half, int len,
    const float* __restrict__ Hws,
    const unsigned char* __restrict__ relL,
    const u32* __restrict__ relW32,
    const float* __restrict__ disc,
    float* __restrict__ pmaxF,            // [2*192]
    const float* __restrict__ updH)
{
    const float NEGINF = -__builtin_inff();
    const int base = w * 48 + half * NJ;

    float hA[NJ], hB[NJ], dreg[NJ];
    {
        const float2* H2 = (const float2*)(Hws + (size_t)b * N_ * 64);
        #pragma unroll
        for (int jj = 0; jj < NJ; ++jj) {
            float2 v = H2[(base + jj) * 32 + p];
            hA[jj] = v.x; hB[jj] = v.y;
            dreg[jj] = disc[base + jj];
        }
    }

    // prologue: pmax[0] over all j (row 0 has no zeroed bytes)
    {
        float mA = NEGINF, mB = NEGINF;
        const u32* rw = (const u32*)(relL + base);
        #pragma unroll
        for (int g = 0; g < NJ / 4; ++g) {
            u32 d = rw[g];
            #pragma unroll
            for (int bb = 0; bb < 4; ++bb) {
                const int jj = 4 * g + bb;
                u32 rr = (d >> (bb * 8)) & 255u;
                u32 pr = relW32[(rr << 5) + p];
                float rwbA = __uint_as_float(pr << 16);
                float rwbB = __uint_as_float(pr & 0xffff0000u);
                float dd = dreg[jj];
                mA = fmaxf(mA, fmaxf(hA[jj] + rwbA, 0.f) * dd);
                mB = fmaxf(mB, fmaxf(hB[jj] + rwbB, 0.f) * dd);
            }
        }
        combine_write(mA, mB, e, pmaxF + (w << 6));
    }
    BARRIER();                                            // prologue barrier

    for (int i = 0; i < len; ++i) {
        if (i > 0) {                                      // merge row i-1
            const int prev = i - 1;
            const int ow = (prev < 48) ? 0 : (prev < 96) ? 1 : 2;
            if (w == ow) {
                float2 u = ((const float2*)updH)[p];
                const int off = prev - ow * 48;
                const int hs = (off >= NJ) ? 1 : 0;
                const int oj = off - hs * NJ;
                if (half == hs) {
                    #pragma unroll
                    for (int jj = 0; jj < NJ; ++jj) if (jj == oj) {
                        hA[jj] = u.x; hB[jj] = u.y;
                    }
                }
            }
        }
        if (i + 1 < len) {                                // pmax for step i+1
            float mA = NEGINF, mB = NEGINF;
            const u32* rw = (const u32*)(relL + (i + 1) * N_ + base);
            #pragma unroll
            for (int g = 0; g < NJ / 4; ++g) {
                u32 d = rw[g];
                #pragma unroll
                for (int bb = 0; bb < 4; ++bb) {
                    const int jj = 4 * g + bb;
                    u32 rr = (d >> (bb * 8)) & 255u;
                    u32 pr = relW32[(rr << 5) + p];
                    float rwbA = __uint_as_float(pr << 16);
                    float rwbB = __uint_as_float(pr & 0xffff0000u);
                    float dd = dreg[jj];
                    mA = fmaxf(mA, fmaxf(hA[jj] + rwbA, 0.f) * dd);
                    mB = fmaxf(mB, fmaxf(hB[jj] + rwbB, 0.f) * dd);
                }
            }
            combine_write(mA, mB, e, pmaxF + ((i & 1) ^ 1) * 192 + (w << 6));
        }
        BARRIER();                                        // step barrier
    }
}

// ---------------- precompute kernel v2 (unchanged) ----------------
__global__ __launch_bounds__(256, 2) void ggnn_pre(
    const int* __restrict__ node_slice, const int* __restrict__ type_slice,
    const float* __restrict__ emb_table, const float* __restrict__ type_table,
    const float* __restrict__ W_in,
    const float* __restrict__ Wr, const float* __restrict__ br,
    const float* __restrict__ Wz, const float* __restrict__ bz,
    const float* __restrict__ Wt, const float* __restrict__ bt,
    u16* __restrict__ NTbf, float* __restrict__ Hws)
{
    const int b  = blockIdx.x >> 4;
    const int i0 = (blockIdx.x & 15) * 8;
    const int t = threadIdx.x;
    const int w = t >> 6;
    const int e = t & 63;

    float wc[96];
    float bias = 0.f;
    if (w < 3) {
        const float* W  = (w == 0) ? Wr : (w == 1) ? Wz : Wt;
        const float* bb = (w == 0) ? br : (w == 1) ? bz : bt;
        bias = bb[e];
        #pragma unroll
        for (int k = 0; k < 96; ++k) wc[k] = W[k * 64 + e];
    } else {
        #pragma unroll
        for (int k = 0; k < 64; ++k) wc[k] = W_in[k * 64 + e];
        #pragma unroll
        for (int k = 64; k < 96; ++k) wc[k] = 0.f;
    }

    int nodes[8], typs[8];
    #pragma unroll
    for (int r = 0; r < 8; ++r) {
        nodes[r] = node_slice[b * N_ + i0 + r];
        typs[r]  = type_slice[b * N_ + i0 + r];
    }

    float xa[8], xb[8];
    #pragma unroll
    for (int r = 0; r < 8; ++r) {
        const float* pa = (e < 32)
            ? (type_table + (size_t)typs[r] * 32 + e)
            : (emb_table + (size_t)nodes[r] * 64 + (e - 32));
        xa[r] = *pa;
        xb[r] = emb_table[(size_t)nodes[r] * 64 + 32 + (e & 31)];
    }

    #pragma unroll
    for (int r = 0; r < 8; ++r) {
        if (w < 3) {
            float a0 = bias, a1 = 0.f, a2 = 0.f, a3 = 0.f;
            #pragma unroll
            for (int k = 0; k < 32; k += 4) {
                a0 += rlane(xa[r], k)     * wc[k];
                a1 += rlane(xa[r], k + 1) * wc[k + 1];
                a2 += rlane(xa[r], k + 2) * wc[k + 2];
                a3 += rlane(xa[r], k + 3) * wc[k + 3];
            }
            #pragma unroll
            for (int k = 0; k < 32; k += 4) {
                a0 += rlane(xa[r], 32 + k)     * wc[32 + k];
                a1 += rlane(xa[r], 32 + k + 1) * wc[32 + k + 1];
                a2 += rlane(xa[r], 32 + k + 2) * wc[32 + k + 2];
                a3 += rlane(xa[r], 32 + k + 3) * wc[32 + k + 3];
            }
            #pragma unroll
            for (int k = 32; k < 64; k += 4) {
                a0 += rlane(xb[r], k - 32) * wc[32 + k];
                a1 += rlane(xb[r], k - 31) * wc[32 + k + 1];
                a2 += rlane(xb[r], k - 30) * wc[32 + k + 2];
                a3 += rlane(xb[r], k - 29) * wc[32 + k + 3];
            }
            NTbf[(size_t)(b * N_ + i0 + r) * 192 + w * 64 + e] =
                f2b((a0 + a1) + (a2 + a3));
        } else {
            float a0 = 0.f, a1 = 0.f, a2 = 0.f, a3 = 0.f;
            #pragma unroll
            for (int k = 0; k < 32; k += 4) {
                a0 += rlane(xa[r], 32 + k)     * wc[k];
                a1 += rlane(xa[r], 32 + k + 1) * wc[k + 1];
                a2 += rlane(xa[r], 32 + k + 2) * wc[k + 2];
                a3 += rlane(xa[r], 32 + k + 3) * wc[k + 3];
            }
            #pragma unroll
            for (int k = 32; k < 64; k += 4) {
                a0 += rlane(xb[r], k - 32) * wc[k];
                a1 += rlane(xb[r], k - 31) * wc[k + 1];
                a2 += rlane(xb[r], k - 30) * wc[k + 2];
                a3 += rlane(xb[r], k - 29) * wc[k + 3];
            }
            Hws[(size_t)(b * N_ + i0 + r) * 64 + e] = (a0 + a1) + (a2 + a3);
        }
    }
}

// ---------------- main scan kernel v11 ----------------
__global__ __launch_bounds__(256, 1) void ggnn_main(
    const int* __restrict__ rel_matrix,
    const int* __restrict__ input_length, const float* __restrict__ distance,
    const float* __restrict__ rel_table,
    const float* __restrict__ W_in, const float* __restrict__ b_in,
    const float* __restrict__ Wr, const float* __restrict__ Wz, const float* __restrict__ Wt,
    const float* __restrict__ W_co, const float* __restrict__ b_co,
    const float* __restrict__ W1, const float* __restrict__ b1,
    const float* __restrict__ W2, const float* __restrict__ b2,
    const float* __restrict__ W3, const float* __restrict__ b3,
    const float* __restrict__ W4, const float* __restrict__ b4,
    const u16* __restrict__ NTbf, const float* __restrict__ Hws,
    float* __restrict__ out)
{
    __shared__ __align__(16) u32   relW32[51 * 32];       // 6.4 KB, [r][e-pair]
    __shared__ __align__(16) unsigned char relL[128 * 128]; // 16 KB, len-masked
    __shared__ __align__(16) float disc[N_];
    __shared__ __align__(16) u32   sub_l[128];            // saved subdiagonal
    __shared__ __align__(16) float pmaxF[2 * 192];        // parity x 3 slots
    __shared__ __align__(16) float updH[64];
    __shared__ __align__(16) float4 wTH[2 * 16 * 64];     // 32 KB: [tbl][kc][e]
    __shared__ __align__(16) float userrow[64], itemrow[64], submrow[64];
    __shared__ __align__(16) float temp[192];
    __shared__ float h1[128];
    __shared__ float h2v[64];
    __shared__ float h3v[32];

    const int b = blockIdx.x;
    const int t = threadIdx.x;
    const int w = t >> 6;          // 0..3
    const int e = t & 63;
    const int p = e & 31;
    const int half = e >> 5;
    const int len = input_length[b];
    const float NEGINF = -__builtin_inff();

    // ---- staging phase 1 ----
    if (t < N_) disc[t] = -0.1f * distance[b * N_ + t];

    {   // rel_matrix -> u8, len-masked
        const int4* src = (const int4*)(rel_matrix + b * N_ * N_);
        u32* dst = (u32*)relL;
        for (int c = t; c < 4096; c += 256) {
            int4 v = src[c];
            int j = (c * 4) & 127;
            u32 pk = (u32)((j + 0 < len && v.x) ? v.x : 0)
                   | ((u32)((j + 1 < len && v.y) ? v.y : 0) << 8)
                   | ((u32)((j + 2 < len && v.z) ? v.z : 0) << 16)
                   | ((u32)((j + 3 < len && v.w) ? v.w : 0) << 24);
            dst[c] = pk;
        }
    }
    for (int idx = t; idx < 51 * 32; idx += 256) {        // relW32 = b_in + rel@W_in_bot
        int r = idx >> 5, pp = idx & 31;
        float aA = b_in[2 * pp], aB = b_in[2 * pp + 1];
        #pragma unroll
        for (int k = 0; k < 32; ++k) {
            float rt = rel_table[r * 32 + k];
            aA += rt * W_in[(64 + k) * 64 + 2 * pp];
            aB += rt * W_in[(64 + k) * 64 + 2 * pp + 1];
        }
        relW32[idx] = (u32)f2b(aA) | ((u32)f2b(aB) << 16);
    }
    {   // wTH: [tbl][kc][e] float4; tbl0 = Wt bottom, tbl1 = W_in top
        float* wf = (float*)wTH;
        for (int idx = t; idx < 8192; idx += 256) {
            int tbl = idx >> 12;
            int rem = idx & 4095;
            int kc  = rem >> 8;
            int ee  = (rem >> 2) & 63;
            int d   = idx & 3;
            int k   = kc * 4 + d;
            wf[idx] = tbl ? W_in[k * 64 + ee] : Wt[(96 + k) * 64 + ee];
        }
    }
    __syncthreads();                                      // staging visible

    // ---- staging phase 2: subdiag save+zero, +INF sentinel ----
    if (t < 127) {
        u32 v = relL[(t + 1) * N_ + t];
        sub_l[t] = v;
        relL[(t + 1) * N_ + t] = 0;
    }
    if (t == 127) sub_l[127] = 0;
    if (t < 32) relW32[t] = 0x7f807f80u;                  // r=0 -> +inf pair
    __syncthreads();

    if (w < 3) {
        // ---- B-waves: H owners + pmax producer ----
        if (w == 2) bloop<16>(b, w, e, p, half, len, Hws, relL, relW32,
                              disc, pmaxF, updH);
        else        bloop<24>(b, w, e, p, half, len, Hws, relL, relW32,
                              disc, pmaxF, updH);
    } else {
        // ---- GRU wave: full chain; wcr/wcz regs, wct/wcH via LDS b128 ----
        float wcr[64], wcz[64];
        #pragma unroll
        for (int k = 0; k < 64; ++k) {
            wcr[k] = Wr[(96 + k) * 64 + e];
            wcz[k] = Wz[(96 + k) * 64 + e];
        }
        const float4* wtL = wTH + e;            // [kc*64 + e]
        const float4* whL = wTH + 1024 + e;     // table 1 offset = 16*64

        const u16* NTb = NTbf + (size_t)b * N_ * 192;
        u16 ncr = NTb[e], ncz = NTb[64 + e], nct = NTb[128 + e];
        float uH = 0.f;
        float user_r = 0.f, item_r = 0.f, subm_r = NEGINF;
        u32 prn = 0x7f807f80u;                  // step-0 patch = no-op
        float ddn = -1.0f;
        BARRIER();                                        // prologue barrier

        for (int i = 0; i < len; ++i) {
            const float* pm = pmaxF + (i & 1) * 192;
            float mm = fmaxf(fmaxf(pm[e], pm[64 + e]), pm[128 + e]);
            {   // fresh-col patch, branch-free (prn=+inf pair -> no-op)
                float rwb = __uint_as_float((e & 1) ? (prn & 0xffff0000u)
                                                    : (prn << 16));
                mm = fmaxf(mm, fmaxf(uH + rwb, 0.f) * ddn);
            }
            float dis0 = (mm == NEGINF) ? 0.f : mm;

            // prefetch patch inputs for step i+1 (static LDS data)
            u32 rb2 = sub_l[i];
            u32 pr2 = relW32[(rb2 << 5) + (e >> 1)];
            float dd2 = disc[i];

            // NT prefetch for step i+1 (global, stays in flight)
            const int nrow = ((i + 1) & 127) * 192;
            u16 npr = NTb[nrow + e], npz = NTb[nrow + 64 + e],
                npt = NTb[nrow + 128 + e];

            // combined r,z matvec (register columns)
            float ra0 = b2f(ncr), ra1 = 0.f, ra2 = 0.f, ra3 = 0.f;
            float za0 = b2f(ncz), za1 = 0.f, za2 = 0.f, za3 = 0.f;
            #pragma unroll
            for (int k = 0; k < 64; k += 4) {
                float s0 = rlane(dis0, k),     s1 = rlane(dis0, k + 1);
                float s2 = rlane(dis0, k + 2), s3 = rlane(dis0, k + 3);
                ra0 += s0 * wcr[k];     za0 += s0 * wcz[k];
                ra1 += s1 * wcr[k + 1]; za1 += s1 * wcz[k + 1];
                ra2 += s2 * wcr[k + 2]; za2 += s2 * wcz[k + 2];
                ra3 += s3 * wcr[k + 3]; za3 += s3 * wcz[k + 3];
            }
            float r = sigmoidf_((ra0 + ra1) + (ra2 + ra3));
            float z = sigmoidf_((za0 + za1) + (za2 + za3));
            float rdp = r * dis0;

            // t matvec (LDS b128 column reads)
            float ta0 = b2f(nct), ta1 = 0.f, ta2 = 0.f, ta3 = 0.f;
            #pragma unroll
            for (int kc = 0; kc < 16; ++kc) {
                float4 wv = wtL[kc * 64];
                float s0 = rlane(rdp, 4 * kc),     s1 = rlane(rdp, 4 * kc + 1);
                float s2 = rlane(rdp, 4 * kc + 2), s3 = rlane(rdp, 4 * kc + 3);
                ta0 += s0 * wv.x; ta1 += s1 * wv.y;
                ta2 += s2 * wv.z; ta3 += s3 * wv.w;
            }
            float hh = tanhf_((ta0 + ta1) + (ta2 + ta3));
            float upd = (1.f - z) * dis0 + z * hh;
            if (i == 0) user_r = upd;
            subm_r = fmaxf(subm_r, upd);
            item_r = upd;

            // H matvec (LDS b128 column reads)
            float ha0 = 0.f, ha1 = 0.f, ha2 = 0.f, ha3 = 0.f;
            #pragma unroll
            for (int kc = 0; kc < 16; ++kc) {
                float4 wv = whL[kc * 64];
                float s0 = rlane(upd, 4 * kc),     s1 = rlane(upd, 4 * kc + 1);
                float s2 = rlane(upd, 4 * kc + 2), s3 = rlane(upd, 4 * kc + 3);
                ha0 += s0 * wv.x; ha1 += s1 * wv.y;
                ha2 += s2 * wv.z; ha3 += s3 * wv.w;
            }
            uH = (ha0 + ha1) + (ha2 + ha3);
            updH[e] = uH;

            ncr = npr; ncz = npz; nct = npt;
            prn = pr2; ddn = dd2;
            BARRIER();                                    // step barrier
        }
        userrow[e] = user_r; itemrow[e] = item_r; submrow[e] = subm_r;
    }
    __syncthreads();

    // ---- epilogue ----
    if (t < 128) {
        const int half2 = t >> 6;               // 0: ua*user, 1: ia*item
        const float* row = (half2 == 0) ? userrow : itemrow;
        float acc = b_co[e];
        #pragma unroll
        for (int k = 0; k < 64; ++k) acc += row[k] * W_co[k * 64 + e];
        #pragma unroll
        for (int k = 0; k < 64; ++k) acc += submrow[k] * W_co[(64 + k) * 64 + e];
        float act = fmaxf(acc, 0.f);
        temp[half2 * 128 + e] = act * row[e];
    } else if (t < 192) {
        temp[64 + (t - 128)] = submrow[t - 128];
    }
    __syncthreads();

    if (t < 128) {
        float acc = b1[t];
        for (int k = 0; k < 192; ++k) acc += temp[k] * W1[k * 128 + t];
        h1[t] = fmaxf(acc, 0.f);
    }
    __syncthreads();
    if (t < 64) {
        float acc = b2[t];
        for (int k = 0; k < 128; ++k) acc += h1[k] * W2[k * 64 + t];
        h2v[t] = fmaxf(acc, 0.f);
    }
    __syncthreads();
    if (t < 32) {
        float acc = b3[t];
        for (int k = 0; k < 64; ++k) acc += h2v[k] * W3[k * 32 + t];
        h3v[t] = fmaxf(acc, 0.f);
    }
    __syncthreads();
    if (t == 0) {
        float acc = b4[0];
        for (int k = 0; k < 32; ++k) acc += h3v[k] * W4[k];
        out[b] = sigmoidf_(acc);
    }
}

extern "C" void kernel_launch(void* const* d_in, const int* in_sizes, int n_in,
                              void* d_out, int out_size, void* d_ws, size_t ws_size,
                              hipStream_t stream)
{
    const int*   node_slice = (const int*)d_in[0];
    const int*   type_slice = (const int*)d_in[1];
    const float* distance   = (const float*)d_in[2];
    const int*   rel_matrix = (const int*)d_in[3];
    const int*   input_len  = (const int*)d_in[4];
    // d_in[5] = isBatch (ignored)
    const float* emb_table  = (const float*)d_in[6];
    const float* type_table = (const float*)d_in[7];
    const float* rel_table  = (const float*)d_in[8];
    const float* W_in = (const float*)d_in[9];  const float* b_in = (const float*)d_in[10];
    const float* Wr   = (const float*)d_in[11]; const float* br   = (const float*)d_in[12];
    const float* Wz   = (const float*)d_in[13]; const float* bz   = (const float*)d_in[14];
    const float* Wt   = (const float*)d_in[15]; const float* bt   = (const float*)d_in[16];
    const float* W_co = (const float*)d_in[17]; const float* b_co = (const float*)d_in[18];
    const float* W1   = (const float*)d_in[19]; const float* b1   = (const float*)d_in[20];
    const float* W2   = (const float*)d_in[21]; const float* b2   = (const float*)d_in[22];
    const float* W3   = (const float*)d_in[23]; const float* b3   = (const float*)d_in[24];
    const float* W4   = (const float*)d_in[25]; const float* b4   = (const float*)d_in[26];

    u16*   NTbf = (u16*)d_ws;                            // 128*128*192 bf16 = 6.29 MB
    float* Hws  = (float*)((char*)d_ws + (size_t)B_ * N_ * 192 * 2); // 4.19 MB

    ggnn_pre<<<dim3(2048), dim3(256), 0, stream>>>(
        node_slice, type_slice, emb_table, type_table,
        W_in, Wr, br, Wz, bz, Wt, bt, NTbf, Hws);

    ggnn_main<<<dim3(B_), dim3(256), 0, stream>>>(
        rel_matrix, input_len, distance, rel_table,
        W_in, b_in, Wr, Wz, Wt, W_co, b_co,
        W1, b1, W2, b2, W3, b3, W4, b4,
        NTbf, Hws, (float*)d_out);
}